// Round 24
// baseline (168.486 us; speedup 1.0000x reference)
//
#include <hip/hip_runtime.h>
#include <hip/hip_bf16.h>
#include <math.h>

#define DD 8192     // sketch dimension d
#define CC 768      // channels
#define SS 145      // sequence length
#define BB 32       // batch
#define SN 64       // sensor dim
#define SROWS 160   // padded s rows (10 tiles of 16)
#define NCKA 24     // A1u chunks (32 c each)

// ---- kD geometry: grid EXACTLY 512 = 2 blocks/CU x 256 CU (no tail) ----
#define NETD 16          // e-tiles of 48
#define TND 48           // e-cols per block
#define NCH 24           // chunks per block (all 768 c)
#define M01W 36          // Mt01 row stride in u32 (144 B)
#define NTD 384          // 6 waves = 3 e-subs x 2 s-halves
#define NWGD (BB*NETD)   // 512 blocks

// ---- kZ geometry ----
#define ZT 512
#define NSL 16

typedef __attribute__((ext_vector_type(8))) short short8;   // 8 bf16
typedef __attribute__((ext_vector_type(4))) float f32x4;    // MFMA acc
typedef __attribute__((ext_vector_type(2))) float f32x2;    // packed fp32

__device__ __forceinline__ void gload16(const void* g, void* l) {
    __builtin_amdgcn_global_load_lds(
        (const __attribute__((address_space(1))) unsigned int*)g,
        (__attribute__((address_space(3))) unsigned int*)l, 16, 0, 0);
}

// ---------------------------------------------------------------------------
// kS body: per-b sketch build. u[b,c]=b_sen[c]+sensor·Wsen[c,:];
// CTG[b][c]=(u1, s1, bits(h1c*8), 0)  [h1 pre-scaled to float2-BYTE offset];
// P2G[b][t]=(S2u_b[t], S2s[t]) fp32 pairs.
// ---------------------------------------------------------------------------
__device__ __forceinline__ void kS_body(
    int b, int tid,
    const float* __restrict__ sensor, const float* __restrict__ Wsen,
    const float* __restrict__ bsen,
    const int* __restrict__ h1, const int* __restrict__ h2,
    const int* __restrict__ s1, const int* __restrict__ s2,
    float4* __restrict__ CTG, float2* __restrict__ P2G, float2* P2l,
    float* sens)
{
    if (tid < SN) sens[tid] = sensor[b*SN + tid];
    {
        float4* p4 = (float4*)P2l;
        #pragma unroll
        for (int i = 0; i < 8; ++i) p4[tid + i*512] = make_float4(0.f,0.f,0.f,0.f);
    }
    __syncthreads();

    for (int c = tid; c < CC; c += 512) {
        float u = bsen[c];
        const float4* w = (const float4*)(Wsen + (size_t)c*SN);
        #pragma unroll
        for (int n4 = 0; n4 < 16; ++n4) {
            float4 wv = w[n4];
            u += sens[4*n4+0]*wv.x + sens[4*n4+1]*wv.y
               + sens[4*n4+2]*wv.z + sens[4*n4+3]*wv.w;
        }
        float f1 = (float)s1[c], f2 = (float)s2[c];
        float4 ct;
        ct.x = u * f1; ct.y = f1; ct.z = __int_as_float(h1[c] << 3); ct.w = 0.f;
        CTG[(size_t)b*CC + c] = ct;
        int t = h2[c];
        unsafeAtomicAdd(&P2l[t].x, u * f2);
        unsafeAtomicAdd(&P2l[t].y, f2);
    }
    __syncthreads();

    {
        const float4* p4 = (const float4*)P2l;
        float4* dst = (float4*)(P2G + (size_t)b*DD);
        #pragma unroll
        for (int i = 0; i < 8; ++i) dst[tid + i*512] = p4[tid + i*512];
    }
}

__device__ __forceinline__ void kA_body(
    int bid, int tid,
    const float* __restrict__ E, const float* __restrict__ tok,
    const int* __restrict__ s1, unsigned int* __restrict__ A1u)
{
    if (tid >= 384) return;
    const int b  = bid / 10;
    const int r0 = (bid % 10) * 16;
    const int c  = 2*tid;
    const int ck = tid >> 4;
    const int c2 = tid & 15;
    const float s1a = (float)s1[c], s1b = (float)s1[c+1];
    const float ta = tok[CC + c] * s1a, tb = tok[CC + c + 1] * s1b;
    #pragma unroll
    for (int rr = 0; rr < 16; ++rr) {
        int row = r0 + rr;
        unsigned int word = 0;
        if (row < SS) {
            float2 ev = *(const float2*)&E[((size_t)b*SS + row)*CC + c];
            __hip_bfloat16 x0 = __float2bfloat16(ev.x*s1a + ta);
            __hip_bfloat16 x1 = __float2bfloat16(ev.y*s1b + tb);
            word = (unsigned int)*(unsigned short*)&x0
                 | ((unsigned int)*(unsigned short*)&x1 << 16);
        }
        int gp = (c2 >> 2) ^ (row & 3);
        A1u[((size_t)(b*NCKA + ck)*SROWS + row)*16 + gp*4 + (c2 & 3)] = word;
    }
}

// ---------------------------------------------------------------------------
// kSA (fused path): blocks [0,320) build A1u; [320,352) per-b sketch (kS);
// block 320 also zeroes Q.
// ---------------------------------------------------------------------------
__global__ __launch_bounds__(512) void kSA(
    const float* __restrict__ sensor, const float* __restrict__ Wsen,
    const float* __restrict__ bsen,
    const int* __restrict__ h1, const int* __restrict__ h2,
    const int* __restrict__ s1, const int* __restrict__ s2,
    float4* __restrict__ CTG, float2* __restrict__ P2G,
    const float* __restrict__ E, const float* __restrict__ tok,
    unsigned int* __restrict__ A1u, float* __restrict__ Q)
{
    __shared__ float2 P2l[DD];
    __shared__ float  sens[SN];
    const int bid = blockIdx.x;
    const int tid = threadIdx.x;
    if (bid < 320) {
        kA_body(bid, tid, E, tok, s1, A1u);
    } else {
        if (bid == 320) for (int i = tid; i < BB*SS; i += 512) Q[i] = 0.f;
        kS_body(bid - 320, tid, sensor, Wsen, bsen, h1, h2, s1, s2,
                CTG, P2G, P2l, sens);
    }
}

// kS standalone (fallback path)
__global__ __launch_bounds__(512) void kS(
    const float* __restrict__ sensor, const float* __restrict__ Wsen,
    const float* __restrict__ bsen,
    const int* __restrict__ h1, const int* __restrict__ h2,
    const int* __restrict__ s1, const int* __restrict__ s2,
    float4* __restrict__ CTG, float2* __restrict__ P2G)
{
    __shared__ float2 P2l[DD];
    __shared__ float  sens[SN];
    kS_body(blockIdx.x, threadIdx.x, sensor, Wsen, bsen, h1, h2, s1, s2,
            CTG, P2G, P2l, sens);
}

// ---------------------------------------------------------------------------
// kZ v6: v3 + CT loads forced onto the VMEM path. The uniform ctp[c] reads
// were s_load (SMEM) which shares lgkmcnt with ds_read -- out-of-order SMEM
// returns force conservative lgkmcnt drains that serialize the gather
// pipeline. An empty inline-asm "+v" constraint pins the base address in a
// VGPR, so the loads become global_load_dwordx4 (vmcnt, L1-hot 12KB table)
// and the ds_read_b64 gathers pipeline independently on lgkmcnt.
// Also (bid==0,tid==0) writes flagP[0] = any(bs2 != 0).
// Writes ZP[b][d]=pack(bf16 Zuu,bf16 Zcr); b==0 also Z11b.
// ---------------------------------------------------------------------------
__global__ __launch_bounds__(ZT) void kZ(
    const float4* __restrict__ CTG, const float2* __restrict__ P2G,
    unsigned int* __restrict__ ZP, unsigned short* __restrict__ Z11b,
    const float* __restrict__ bs2, int* __restrict__ flagP)
{
    __shared__ float2 P2l[DD];        // 64 KB -> 2 blocks/CU

    const int bid = blockIdx.x;
    const int wg  = (bid & 7)*(BB*NSL/8) + (bid >> 3);
    const int b   = wg >> 4;
    const int dsl = wg & (NSL-1);
    const int tid = threadIdx.x;
    const bool doZ11 = (b == 0);

    if (bid == 0 && tid == 0) {
        int f = 0;
        for (int s = 0; s < SS; ++s) f |= (bs2[s] != 0.f) ? 1 : 0;
        *flagP = f;
    }

    {
        const float4* src = (const float4*)(P2G + (size_t)b*DD);
        float4* dst = (float4*)P2l;
        #pragma unroll
        for (int i = 0; i < 8; ++i) dst[tid + i*ZT] = src[tid + i*ZT];
    }
    __syncthreads();

    const int d  = dsl*ZT + tid;
    const int d8 = d << 3;                     // byte offset of own float2
    // Force CT base into a VGPR -> VMEM (vmcnt) loads, decoupled from LDS
    unsigned long long ctpa = (unsigned long long)(CTG + (size_t)b*CC);
    asm volatile("" : "+v"(ctpa));
    const float4* ctp = (const float4*)ctpa;

    f32x2 accP = {0.f, 0.f};                   // (accU, accC_a)
    float accC2 = 0.f, acc1 = 0.f;
    #pragma unroll 8
    for (int c = 0; c < CC; ++c) {
        float4 ct = ctp[c];                    // global_load_dwordx4 (vmcnt)
        int ab = (d8 - __float_as_int(ct.z)) & 65535;   // ((d-h1c)&8191)*8
        f32x2 p = *(const f32x2*)((const char*)P2l + ab);
        f32x2 uu = {ct.x, ct.x};
        accP = __builtin_elementwise_fma(uu, p, accP);  // v_pk_fma_f32
        accC2 = fmaf(ct.y, p.x, accC2);
        if (doZ11) acc1 = fmaf(ct.y, p.y, acc1);
    }
    float accU = accP.x, accC = accP.y + accC2;

    __hip_bfloat16 zu = __float2bfloat16(accU);
    __hip_bfloat16 zc = __float2bfloat16(accC);
    ZP[(size_t)b*DD + d] = (unsigned int)*(unsigned short*)&zu
                         | ((unsigned int)*(unsigned short*)&zc << 16);
    if (doZ11) {
        __hip_bfloat16 z1 = __float2bfloat16(acc1);
        Z11b[d] = *(unsigned short*)&z1;
    }
}

// ---------------------------------------------------------------------------
// kM11: materialize b-independent m=2 matrix (24 blocks). Skipped entirely
// when bs2 == 0 (M11 is then multiplied by bb^2 = 0 and never read).
// ---------------------------------------------------------------------------
__global__ __launch_bounds__(512) void kM11(
    const unsigned short* __restrict__ Z11b,
    const int* __restrict__ h1, const int* __restrict__ h2,
    unsigned int* __restrict__ M11u, const int* __restrict__ flagP)
{
    __shared__ unsigned short Z11l[DD];
    if (*flagP == 0) return;
    const int ck  = blockIdx.x;
    const int tid = threadIdx.x;
    {
        const uint4* src = (const uint4*)Z11b;
        uint4* dst = (uint4*)Z11l;
        #pragma unroll
        for (int i = 0; i < 2; ++i) dst[tid + i*512] = src[tid + i*512];
    }
    __syncthreads();

    #pragma unroll 4
    for (int i = 0; i < 24; ++i) {
        int idx = tid + i*512;
        int ep  = idx >> 4;
        int cpp = idx & 15;
        int ha = h1[ck*32 + 2*cpp];
        int hb = h1[ck*32 + 2*cpp + 1];
        int he = h2[ep];
        unsigned int lo = Z11l[(ha + he) & (DD-1)];
        unsigned int hi = Z11l[(hb + he) & (DD-1)];
        M11u[((size_t)ck*768 + ep)*16 + cpp] = lo | (hi << 16);
    }
}

// kAM (fallback path): kA + kM11 fused; kM11 part honors the flag.
__global__ __launch_bounds__(512) void kAM(
    const float* __restrict__ E, const float* __restrict__ tok,
    const int* __restrict__ s1, unsigned int* __restrict__ A1u,
    const unsigned short* __restrict__ Z11b,
    const int* __restrict__ h1, const int* __restrict__ h2,
    unsigned int* __restrict__ M11u, const int* __restrict__ flagP)
{
    __shared__ unsigned short Z11l[DD];
    const int bid = blockIdx.x;
    const int tid = threadIdx.x;
    if (bid < 320) {
        kA_body(bid, tid, E, tok, s1, A1u);
    } else {
        if (*flagP == 0) return;
        const int ck = bid - 320;
        {
            const uint4* src = (const uint4*)Z11b;
            uint4* dst = (uint4*)Z11l;
            #pragma unroll
            for (int i = 0; i < 2; ++i) dst[tid + i*512] = src[tid + i*512];
        }
        __syncthreads();
        #pragma unroll 4
        for (int i = 0; i < 24; ++i) {
            int idx = tid + i*512;
            int ep  = idx >> 4;
            int cpp = idx & 15;
            int ha = h1[ck*32 + 2*cpp];
            int hb = h1[ck*32 + 2*cpp + 1];
            int he = h2[ep];
            unsigned int lo = Z11l[(ha + he) & (DD-1)];
            unsigned int hi = Z11l[(hb + he) & (DD-1)];
            M11u[((size_t)ck*768 + ep)*16 + cpp] = lo | (hi << 16);
        }
    }
}

// ---------------------------------------------------------------------------
// kD: fused 3-form MFMA; grid 512 no-tail, dbuf Lt/Mt01. When flag==0
// (bs2 all zero), the m=1/m=2 forms are exactly 0: reduced loop with
// 5 MFMA/chunk (b0 only), no M11 loads, vmcnt(0) barriers. Otherwise the
// proven full loop (15 MFMA, counted vmcnt(1)).
// ---------------------------------------------------------------------------
__global__ __launch_bounds__(NTD, 4) void kD(
    const unsigned int* __restrict__ A1u,
    const unsigned short* __restrict__ M11,
    const float* __restrict__ E, const float* __restrict__ tok,
    const int* __restrict__ h1, const int* __restrict__ h2,
    const int* __restrict__ s2,
    const float* __restrict__ Ws2, const float* __restrict__ bs2,
    const unsigned int* __restrict__ ZP, float* __restrict__ Q,
    const int* __restrict__ flagP)
{
    __shared__ __align__(16) unsigned int   ZPl[DD];           // 32768 B
    __shared__ __align__(16) unsigned short Lt[2][SROWS*32];   // 20480 B
    __shared__ __align__(16) unsigned int   Mt01[2][TND*M01W]; // 13824 B
    __shared__ unsigned short h1l[CC];                         //  1536 B

    const int bid = blockIdx.x;
    const int wg  = (bid & 7)*(NWGD/8) + (bid >> 3);
    const int b   = wg / NETD;
    const int et  = wg % NETD;
    const int tid = threadIdx.x;
    const int e0  = et * TND;
    const int fl  = *flagP;

    {
        const uint4* src = (const uint4*)(ZP + (size_t)b*DD);
        uint4* dst = (uint4*)ZPl;
        for (int i = tid; i < DD/4; i += NTD) dst[i] = src[i];
    }
    for (int c = tid; c < CC; c += NTD) h1l[c] = (unsigned short)h1[c];

    const int lane = tid & 63;
    const int wv   = tid >> 6;        // wave 0..5
    const int esub = wv % 3;          // e-sub-tile (16 cols)
    const int shf  = wv / 3;          // s-half
    const int l15  = lane & 15;
    const int l4   = lane >> 4;
    const int eg   = e0 + esub*16 + l15;

    int gh2[4];
    #pragma unroll
    for (int j = 0; j < 4; ++j) gh2[j] = h2[e0 + ((tid + j*NTD) >> 5)];
    __syncthreads();

    const char* Abase = (const char*)A1u + (size_t)b*NCKA*SROWS*64;

#define BARC() do { \
    asm volatile("s_waitcnt vmcnt(1) lgkmcnt(0)" ::: "memory"); \
    __builtin_amdgcn_sched_barrier(0); \
    __builtin_amdgcn_s_barrier(); \
    __builtin_amdgcn_sched_barrier(0); \
} while (0)

#define BARC0() do { \
    asm volatile("s_waitcnt vmcnt(0) lgkmcnt(0)" ::: "memory"); \
    __builtin_amdgcn_sched_barrier(0); \
    __builtin_amdgcn_s_barrier(); \
    __builtin_amdgcn_sched_barrier(0); \
} while (0)

#define STAGE_A(K, BUF) { \
    const char* cbase = Abase + (size_t)(K)*SROWS*64; \
    gload16(cbase + wv*1024 + lane*16, (char*)(BUF) + wv*1024); \
    if (wv < 4) \
        gload16(cbase + 6144 + wv*1024 + lane*16, \
                (char*)(BUF) + 6144 + wv*1024); \
    }

#define GATHER(K, MT) { \
    _Pragma("unroll") \
    for (int j = 0; j < 4; ++j) { \
        int idx = tid + j*NTD; \
        int ge = idx >> 5, gc = idx & 31; \
        int ad = ((int)h1l[(K)*32 + gc] + gh2[j]) & (DD-1); \
        MT[ge*M01W + gc] = ZPl[ad]; \
    } }

#define LOADB2(K) \
    (*(const short8*)&M11[((size_t)(K)*768 + eg)*32 + l4*8])

#define MFMA_STEP(LT, MT, BQ) { \
    const unsigned int* mp = &MT[(esub*16 + l15)*M01W + l4*8]; \
    uint4 p0 = *(const uint4*)mp; \
    uint4 p1 = *(const uint4*)(mp + 4); \
    union { unsigned int u[4]; short8 s; } b0, b1; \
    b0.u[0] = (p0.x & 0xffffu) | (p0.y << 16); \
    b1.u[0] = (p0.x >> 16)     | (p0.y & 0xffff0000u); \
    b0.u[1] = (p0.z & 0xffffu) | (p0.w << 16); \
    b1.u[1] = (p0.z >> 16)     | (p0.w & 0xffff0000u); \
    b0.u[2] = (p1.x & 0xffffu) | (p1.y << 16); \
    b1.u[2] = (p1.x >> 16)     | (p1.y & 0xffff0000u); \
    b0.u[3] = (p1.z & 0xffffu) | (p1.w << 16); \
    b1.u[3] = (p1.z >> 16)     | (p1.w & 0xffff0000u); \
    _Pragma("unroll") \
    for (int t = 0; t < 5; ++t) { \
        int R = shf*80 + t*16 + l15; \
        short8 af = *(const short8*)&LT[R*32 + ((l4 ^ (R & 3))*8)]; \
        acc0[t] = __builtin_amdgcn_mfma_f32_16x16x32_bf16(af, b0.s, acc0[t], 0,0,0); \
        acc1[t] = __builtin_amdgcn_mfma_f32_16x16x32_bf16(af, b1.s, acc1[t], 0,0,0); \
        acc2[t] = __builtin_amdgcn_mfma_f32_16x16x32_bf16(af, BQ,   acc2[t], 0,0,0); \
    } }

#define MFMA_STEP0(LT, MT) { \
    const unsigned int* mp = &MT[(esub*16 + l15)*M01W + l4*8]; \
    uint4 p0 = *(const uint4*)mp; \
    uint4 p1 = *(const uint4*)(mp + 4); \
    union { unsigned int u[4]; short8 s; } b0; \
    b0.u[0] = (p0.x & 0xffffu) | (p0.y << 16); \
    b0.u[1] = (p0.z & 0xffffu) | (p0.w << 16); \
    b0.u[2] = (p1.x & 0xffffu) | (p1.y << 16); \
    b0.u[3] = (p1.z & 0xffffu) | (p1.w << 16); \
    _Pragma("unroll") \
    for (int t = 0; t < 5; ++t) { \
        int R = shf*80 + t*16 + l15; \
        short8 af = *(const short8*)&LT[R*32 + ((l4 ^ (R & 3))*8)]; \
        acc0[t] = __builtin_amdgcn_mfma_f32_16x16x32_bf16(af, b0.s, acc0[t], 0,0,0); \
    } }

    f32x4 acc0[5], acc1[5], acc2[5];
    #pragma unroll
    for (int t = 0; t < 5; ++t) {
        acc0[t] = (f32x4){0.f,0.f,0.f,0.f};
        acc1[t] = (f32x4){0.f,0.f,0.f,0.f};
        acc2[t] = (f32x4){0.f,0.f,0.f,0.f};
    }

    if (fl) {
        short8 bqA, bqB;
        STAGE_A(0, Lt[0])
        GATHER(0, Mt01[0])
        __builtin_amdgcn_sched_barrier(0);
        bqA = LOADB2(0);
        BARC();

        #pragma unroll 1
        for (int k = 0; k < NCH; k += 2) {
            if (k + 1 < NCH) {
                STAGE_A(k + 1, Lt[1])
                GATHER(k + 1, Mt01[1])
                __builtin_amdgcn_sched_barrier(0);
                bqB = LOADB2(k + 1);
            }
            MFMA_STEP(Lt[0], Mt01[0], bqA)
            BARC();

            if (k + 2 < NCH) {
                STAGE_A(k + 2, Lt[0])
                GATHER(k + 2, Mt01[0])
                __builtin_amdgcn_sched_barrier(0);
                bqA = LOADB2(k + 2);
            }
            if (k + 1 < NCH) {
                MFMA_STEP(Lt[1], Mt01[1], bqB)
            }
            BARC();
        }
    } else {
        STAGE_A(0, Lt[0])
        GATHER(0, Mt01[0])
        BARC0();

        #pragma unroll 1
        for (int k = 0; k < NCH; k += 2) {
            if (k + 1 < NCH) {
                STAGE_A(k + 1, Lt[1])
                GATHER(k + 1, Mt01[1])
            }
            MFMA_STEP0(Lt[0], Mt01[0])
            BARC0();

            if (k + 2 < NCH) {
                STAGE_A(k + 2, Lt[0])
                GATHER(k + 2, Mt01[0])
            }
            if (k + 1 < NCH) {
                MFMA_STEP0(Lt[1], Mt01[1])
            }
            BARC0();
        }
    }
#undef BARC
#undef BARC0
#undef STAGE_A
#undef GATHER
#undef LOADB2
#undef MFMA_STEP
#undef MFMA_STEP0

    // --- epilogue: combine 3 forms (acc1/acc2 zero on reduced path),
    //     reduce 16 e-lanes, one atomic ---
    const float s2e = (float)s2[eg];
    const float t2e = tok[CC + eg] * s2e;
    #pragma unroll
    for (int t = 0; t < 5; ++t) {
        #pragma unroll
        for (int rr = 0; rr < 4; ++rr) {
            int s = shf*80 + t*16 + l4*4 + rr;
            float qv = 0.f;
            if (s < SS) {
                float a2v = E[((size_t)b*SS + s)*CC + eg] * s2e + t2e;
                float w2v = Ws2[s], bbv = bs2[s];
                qv = (w2v*w2v*acc0[t][rr] + w2v*bbv*acc1[t][rr]
                      + bbv*bbv*acc2[t][rr]) * a2v;
            }
            qv += __shfl_xor(qv, 1);
            qv += __shfl_xor(qv, 2);
            qv += __shfl_xor(qv, 4);
            qv += __shfl_xor(qv, 8);
            if (l15 == 0 && s < SS)
                unsafeAtomicAdd(&Q[b*SS + s], qv);
        }
    }
}

// ---------------------------------------------------------------------------
// kE: bp = sign(Q)*sqrt(|Q|+1e-5); L2-normalize over s; project W_out.
// ---------------------------------------------------------------------------
__global__ __launch_bounds__(256) void kE(
    const float* __restrict__ Q, const float* __restrict__ Wout,
    const float* __restrict__ bout, float* __restrict__ out)
{
    __shared__ float red[8];
    const int b = blockIdx.x, tid = threadIdx.x;
    float v = 0.f, w = 0.f;
    if (tid < SS) {
        float ip = Q[b*SS + tid];
        float sg = (ip > 0.f) ? 1.f : ((ip < 0.f) ? -1.f : 0.f);
        v = sg * sqrtf(fabsf(ip) + 1e-5f);
        w = v * Wout[tid];
    }
    float sq = v * v;
    #pragma unroll
    for (int off = 32; off > 0; off >>= 1) {
        sq += __shfl_down(sq, off, 64);
        w  += __shfl_down(w,  off, 64);
    }
    if ((tid & 63) == 0) { red[tid >> 6] = sq; red[4 + (tid >> 6)] = w; }
    __syncthreads();
    if (tid == 0) {
        float ssq  = red[0] + red[1] + red[2] + red[3];
        float sw   = red[4] + red[5] + red[6] + red[7];
        float norm = fmaxf(sqrtf(ssq), 1e-12f);
        out[b] = sw / norm + bout[0];
    }
}

// ---------------------------------------------------------------------------
extern "C" void kernel_launch(void* const* d_in, const int* in_sizes, int n_in,
                              void* d_out, int out_size, void* d_ws, size_t ws_size,
                              hipStream_t stream) {
    const float* sensor = (const float*)d_in[0];
    const float* E      = (const float*)d_in[1];
    const int*   h1     = (const int*)d_in[3];
    const int*   h2     = (const int*)d_in[4];
    const int*   s1     = (const int*)d_in[5];
    const int*   s2     = (const int*)d_in[6];
    const float* Wsen   = (const float*)d_in[8];
    const float* bsen   = (const float*)d_in[9];
    const float* Ws2    = (const float*)d_in[10];
    const float* bs2    = (const float*)d_in[11];
    const float* Wout   = (const float*)d_in[12];
    const float* bout   = (const float*)d_in[13];
    const float* tok    = (const float*)d_in[14];
    float* out = (float*)d_out;

    char* ws = (char*)d_ws;
    const size_t SZ_CTG  = (size_t)BB*CC*16;        //   393,216
    const size_t SZ_P2G  = (size_t)BB*DD*8;         // 2,097,152
    const size_t SZ_ZP   = (size_t)BB*DD*4;         // 1,048,576
    const size_t SZ_Z11  = (size_t)DD*2;            //    16,384
    const size_t SZ_M11  = (size_t)NCKA*768*64;     // 1,179,648
    const size_t SZ_Q    = (size_t)BB*SS*4;         //    18,560
    const size_t SZ_FLAG = 64;
    const size_t SZ_A1   = (size_t)BB*NCKA*SROWS*64;// 7,864,320
    const size_t needFused =
        SZ_CTG+SZ_P2G+SZ_ZP+SZ_Z11+SZ_M11+SZ_Q+SZ_FLAG+SZ_A1;

    if (ws_size >= needFused) {
        // ---- fused path: A1u non-aliased, kA runs concurrently with kS ----
        float4* CTG = (float4*)ws;
        float2* P2G = (float2*)(ws + SZ_CTG);
        unsigned int*   ZP   = (unsigned int*)(ws + SZ_CTG + SZ_P2G);
        unsigned short* Z11b = (unsigned short*)((char*)ZP + SZ_ZP);
        unsigned int*   M11u = (unsigned int*)((char*)Z11b + SZ_Z11);
        float*          Q    = (float*)((char*)M11u + SZ_M11);
        int*            flagP= (int*)((char*)Q + SZ_Q);
        unsigned int*   A1u  = (unsigned int*)((char*)flagP + SZ_FLAG);

        kSA<<<dim3(352), dim3(512), 0, stream>>>(
            sensor, Wsen, bsen, h1, h2, s1, s2, CTG, P2G, E, tok, A1u, Q);
        kZ<<<dim3(BB*NSL), dim3(ZT), 0, stream>>>(
            CTG, P2G, ZP, Z11b, bs2, flagP);
        kM11<<<dim3(NCKA), dim3(512), 0, stream>>>(Z11b, h1, h2, M11u, flagP);
        kD<<<dim3(NWGD), dim3(NTD), 0, stream>>>(
            A1u, (const unsigned short*)M11u, E, tok, h1, h2, s2,
            Ws2, bs2, ZP, Q, flagP);
        kE<<<dim3(BB), dim3(256), 0, stream>>>(Q, Wout, bout, out);
    } else {
        // ---- fallback: A1u aliases CTG/P2G after kZ ----
        float4* CTG = (float4*)ws;
        float2* P2G = (float2*)(ws + SZ_CTG);
        unsigned int* A1u = (unsigned int*)ws;
        unsigned int*   ZP   = (unsigned int*)(ws + SZ_A1);
        unsigned short* Z11b = (unsigned short*)(ws + SZ_A1 + SZ_ZP);
        unsigned int*   M11u = (unsigned int*)((char*)Z11b + SZ_Z11);
        float* Q = (float*)((char*)M11u + SZ_M11);
        int*   flagP = (int*)((char*)Q + SZ_Q);

        hipMemsetAsync(Q, 0, SZ_Q, stream);
        kS<<<dim3(BB), dim3(512), 0, stream>>>(
            sensor, Wsen, bsen, h1, h2, s1, s2, CTG, P2G);
        kZ<<<dim3(BB*NSL), dim3(ZT), 0, stream>>>(
            CTG, P2G, ZP, Z11b, bs2, flagP);
        kAM<<<dim3(344), dim3(512), 0, stream>>>(
            E, tok, s1, A1u, Z11b, h1, h2, M11u, flagP);
        kD<<<dim3(NWGD), dim3(NTD), 0, stream>>>(
            A1u, (const unsigned short*)M11u, E, tok, h1, h2, s2,
            Ws2, bs2, ZP, Q, flagP);
        kE<<<dim3(BB), dim3(256), 0, stream>>>(Q, Wout, bout, out);
    }
}

// Round 25
// 141.061 us; speedup vs baseline: 1.1944x; 1.1944x over previous
//
#include <hip/hip_runtime.h>
#include <hip/hip_bf16.h>
#include <math.h>

#define DD 8192     // sketch dimension d
#define CC 768      // channels
#define SS 145      // sequence length
#define BB 32       // batch
#define SN 64       // sensor dim
#define SROWS 160   // padded s rows (10 tiles of 16)
#define NCKA 24     // A1u chunks (32 c each)

// ---- kD geometry: grid EXACTLY 512 = 2 blocks/CU x 256 CU (no tail) ----
#define NETD 16          // e-tiles of 48
#define TND 48           // e-cols per block
#define NCH 24           // chunks per block (all 768 c)
#define M01W 36          // Mt01 row stride in u32 (144 B)
#define NTD 384          // 6 waves = 3 e-subs x 2 s-halves
#define NWGD (BB*NETD)   // 512 blocks

// ---- kZ geometry ----
#define ZT 512
#define NSL 16

typedef __attribute__((ext_vector_type(8))) short short8;   // 8 bf16
typedef __attribute__((ext_vector_type(4))) float f32x4;    // MFMA acc
typedef __attribute__((ext_vector_type(2))) float f32x2;    // packed fp32

__device__ __forceinline__ void gload16(const void* g, void* l) {
    __builtin_amdgcn_global_load_lds(
        (const __attribute__((address_space(1))) unsigned int*)g,
        (__attribute__((address_space(3))) unsigned int*)l, 16, 0, 0);
}

// ---------------------------------------------------------------------------
// kS body: per-b sketch build. u[b,c]=b_sen[c]+sensor·Wsen[c,:];
// CTG[b][c]=(u1, s1, bits(h1c*8), 0)  [h1 pre-scaled to float2-BYTE offset];
// P2G[b][t]=(S2u_b[t], S2s[t]) fp32 pairs.
// ---------------------------------------------------------------------------
__device__ __forceinline__ void kS_body(
    int b, int tid,
    const float* __restrict__ sensor, const float* __restrict__ Wsen,
    const float* __restrict__ bsen,
    const int* __restrict__ h1, const int* __restrict__ h2,
    const int* __restrict__ s1, const int* __restrict__ s2,
    float4* __restrict__ CTG, float2* __restrict__ P2G, float2* P2l,
    float* sens)
{
    if (tid < SN) sens[tid] = sensor[b*SN + tid];
    {
        float4* p4 = (float4*)P2l;
        #pragma unroll
        for (int i = 0; i < 8; ++i) p4[tid + i*512] = make_float4(0.f,0.f,0.f,0.f);
    }
    __syncthreads();

    for (int c = tid; c < CC; c += 512) {
        float u = bsen[c];
        const float4* w = (const float4*)(Wsen + (size_t)c*SN);
        #pragma unroll
        for (int n4 = 0; n4 < 16; ++n4) {
            float4 wv = w[n4];
            u += sens[4*n4+0]*wv.x + sens[4*n4+1]*wv.y
               + sens[4*n4+2]*wv.z + sens[4*n4+3]*wv.w;
        }
        float f1 = (float)s1[c], f2 = (float)s2[c];
        float4 ct;
        ct.x = u * f1; ct.y = f1; ct.z = __int_as_float(h1[c] << 3); ct.w = 0.f;
        CTG[(size_t)b*CC + c] = ct;
        int t = h2[c];
        unsafeAtomicAdd(&P2l[t].x, u * f2);
        unsafeAtomicAdd(&P2l[t].y, f2);
    }
    __syncthreads();

    {
        const float4* p4 = (const float4*)P2l;
        float4* dst = (float4*)(P2G + (size_t)b*DD);
        #pragma unroll
        for (int i = 0; i < 8; ++i) dst[tid + i*512] = p4[tid + i*512];
    }
}

__device__ __forceinline__ void kA_body(
    int bid, int tid,
    const float* __restrict__ E, const float* __restrict__ tok,
    const int* __restrict__ s1, unsigned int* __restrict__ A1u)
{
    if (tid >= 384) return;
    const int b  = bid / 10;
    const int r0 = (bid % 10) * 16;
    const int c  = 2*tid;
    const int ck = tid >> 4;
    const int c2 = tid & 15;
    const float s1a = (float)s1[c], s1b = (float)s1[c+1];
    const float ta = tok[CC + c] * s1a, tb = tok[CC + c + 1] * s1b;
    #pragma unroll
    for (int rr = 0; rr < 16; ++rr) {
        int row = r0 + rr;
        unsigned int word = 0;
        if (row < SS) {
            float2 ev = *(const float2*)&E[((size_t)b*SS + row)*CC + c];
            __hip_bfloat16 x0 = __float2bfloat16(ev.x*s1a + ta);
            __hip_bfloat16 x1 = __float2bfloat16(ev.y*s1b + tb);
            word = (unsigned int)*(unsigned short*)&x0
                 | ((unsigned int)*(unsigned short*)&x1 << 16);
        }
        int gp = (c2 >> 2) ^ (row & 3);
        A1u[((size_t)(b*NCKA + ck)*SROWS + row)*16 + gp*4 + (c2 & 3)] = word;
    }
}

// ---------------------------------------------------------------------------
// kSA (fused path): blocks [0,320) build A1u; [320,352) per-b sketch (kS);
// block 320 also zeroes Q.
// ---------------------------------------------------------------------------
__global__ __launch_bounds__(512) void kSA(
    const float* __restrict__ sensor, const float* __restrict__ Wsen,
    const float* __restrict__ bsen,
    const int* __restrict__ h1, const int* __restrict__ h2,
    const int* __restrict__ s1, const int* __restrict__ s2,
    float4* __restrict__ CTG, float2* __restrict__ P2G,
    const float* __restrict__ E, const float* __restrict__ tok,
    unsigned int* __restrict__ A1u, float* __restrict__ Q)
{
    __shared__ float2 P2l[DD];
    __shared__ float  sens[SN];
    const int bid = blockIdx.x;
    const int tid = threadIdx.x;
    if (bid < 320) {
        kA_body(bid, tid, E, tok, s1, A1u);
    } else {
        if (bid == 320) for (int i = tid; i < BB*SS; i += 512) Q[i] = 0.f;
        kS_body(bid - 320, tid, sensor, Wsen, bsen, h1, h2, s1, s2,
                CTG, P2G, P2l, sens);
    }
}

// kS standalone (fallback path)
__global__ __launch_bounds__(512) void kS(
    const float* __restrict__ sensor, const float* __restrict__ Wsen,
    const float* __restrict__ bsen,
    const int* __restrict__ h1, const int* __restrict__ h2,
    const int* __restrict__ s1, const int* __restrict__ s2,
    float4* __restrict__ CTG, float2* __restrict__ P2G)
{
    __shared__ float2 P2l[DD];
    __shared__ float  sens[SN];
    kS_body(blockIdx.x, threadIdx.x, sensor, Wsen, bsen, h1, h2, s1, s2,
            CTG, P2G, P2l, sens);
}

// ---------------------------------------------------------------------------
// kZ v3 + flag (proven best): 512 thr, 768 iters, unroll 4; byte-offset
// address (sub+and, h1 pre-scaled in kS); packed v_pk_fma_f32 for
// (accU, accC_a); scalar fma for accC_b. Conflict-free b64 gathers.
// Also (bid==0,tid==0) scans bs2 and writes flagP[0] = any(bs2 != 0).
// Writes ZP[b][d]=pack(bf16 Zuu,bf16 Zcr); b==0 also Z11b.
// ---------------------------------------------------------------------------
__global__ __launch_bounds__(ZT) void kZ(
    const float4* __restrict__ CTG, const float2* __restrict__ P2G,
    unsigned int* __restrict__ ZP, unsigned short* __restrict__ Z11b,
    const float* __restrict__ bs2, int* __restrict__ flagP)
{
    __shared__ float2 P2l[DD];        // 64 KB -> 2 blocks/CU

    const int bid = blockIdx.x;
    const int wg  = (bid & 7)*(BB*NSL/8) + (bid >> 3);
    const int b   = wg >> 4;
    const int dsl = wg & (NSL-1);
    const int tid = threadIdx.x;
    const bool doZ11 = (b == 0);

    if (bid == 0 && tid == 0) {
        int f = 0;
        for (int s = 0; s < SS; ++s) f |= (bs2[s] != 0.f) ? 1 : 0;
        *flagP = f;
    }

    {
        const float4* src = (const float4*)(P2G + (size_t)b*DD);
        float4* dst = (float4*)P2l;
        #pragma unroll
        for (int i = 0; i < 8; ++i) dst[tid + i*ZT] = src[tid + i*ZT];
    }
    __syncthreads();

    const int d  = dsl*ZT + tid;
    const int d8 = d << 3;                     // byte offset of own float2
    const float4* ctp = CTG + (size_t)b*CC;
    f32x2 accP = {0.f, 0.f};                   // (accU, accC_a)
    float accC2 = 0.f, acc1 = 0.f;
    #pragma unroll 4
    for (int c = 0; c < CC; ++c) {
        float4 ct = ctp[c];                    // uniform -> s_load path
        int ab = (d8 - __float_as_int(ct.z)) & 65535;   // ((d-h1c)&8191)*8
        f32x2 p = *(const f32x2*)((const char*)P2l + ab);
        f32x2 uu = {ct.x, ct.x};
        accP = __builtin_elementwise_fma(uu, p, accP);  // v_pk_fma_f32
        accC2 = fmaf(ct.y, p.x, accC2);
        if (doZ11) acc1 = fmaf(ct.y, p.y, acc1);
    }
    float accU = accP.x, accC = accP.y + accC2;

    __hip_bfloat16 zu = __float2bfloat16(accU);
    __hip_bfloat16 zc = __float2bfloat16(accC);
    ZP[(size_t)b*DD + d] = (unsigned int)*(unsigned short*)&zu
                         | ((unsigned int)*(unsigned short*)&zc << 16);
    if (doZ11) {
        __hip_bfloat16 z1 = __float2bfloat16(acc1);
        Z11b[d] = *(unsigned short*)&z1;
    }
}

// ---------------------------------------------------------------------------
// kM11: materialize b-independent m=2 matrix (24 blocks). Skipped entirely
// when bs2 == 0 (M11 is then multiplied by bb^2 = 0 and never read).
// ---------------------------------------------------------------------------
__global__ __launch_bounds__(512) void kM11(
    const unsigned short* __restrict__ Z11b,
    const int* __restrict__ h1, const int* __restrict__ h2,
    unsigned int* __restrict__ M11u, const int* __restrict__ flagP)
{
    __shared__ unsigned short Z11l[DD];
    if (*flagP == 0) return;
    const int ck  = blockIdx.x;
    const int tid = threadIdx.x;
    {
        const uint4* src = (const uint4*)Z11b;
        uint4* dst = (uint4*)Z11l;
        #pragma unroll
        for (int i = 0; i < 2; ++i) dst[tid + i*512] = src[tid + i*512];
    }
    __syncthreads();

    #pragma unroll 4
    for (int i = 0; i < 24; ++i) {
        int idx = tid + i*512;
        int ep  = idx >> 4;
        int cpp = idx & 15;
        int ha = h1[ck*32 + 2*cpp];
        int hb = h1[ck*32 + 2*cpp + 1];
        int he = h2[ep];
        unsigned int lo = Z11l[(ha + he) & (DD-1)];
        unsigned int hi = Z11l[(hb + he) & (DD-1)];
        M11u[((size_t)ck*768 + ep)*16 + cpp] = lo | (hi << 16);
    }
}

// kAM (fallback path): kA + kM11 fused; kM11 part honors the flag.
__global__ __launch_bounds__(512) void kAM(
    const float* __restrict__ E, const float* __restrict__ tok,
    const int* __restrict__ s1, unsigned int* __restrict__ A1u,
    const unsigned short* __restrict__ Z11b,
    const int* __restrict__ h1, const int* __restrict__ h2,
    unsigned int* __restrict__ M11u, const int* __restrict__ flagP)
{
    __shared__ unsigned short Z11l[DD];
    const int bid = blockIdx.x;
    const int tid = threadIdx.x;
    if (bid < 320) {
        kA_body(bid, tid, E, tok, s1, A1u);
    } else {
        if (*flagP == 0) return;
        const int ck = bid - 320;
        {
            const uint4* src = (const uint4*)Z11b;
            uint4* dst = (uint4*)Z11l;
            #pragma unroll
            for (int i = 0; i < 2; ++i) dst[tid + i*512] = src[tid + i*512];
        }
        __syncthreads();
        #pragma unroll 4
        for (int i = 0; i < 24; ++i) {
            int idx = tid + i*512;
            int ep  = idx >> 4;
            int cpp = idx & 15;
            int ha = h1[ck*32 + 2*cpp];
            int hb = h1[ck*32 + 2*cpp + 1];
            int he = h2[ep];
            unsigned int lo = Z11l[(ha + he) & (DD-1)];
            unsigned int hi = Z11l[(hb + he) & (DD-1)];
            M11u[((size_t)ck*768 + ep)*16 + cpp] = lo | (hi << 16);
        }
    }
}

// ---------------------------------------------------------------------------
// kD: fused 3-form MFMA; grid 512 no-tail, dbuf Lt/Mt01. When flag==0
// (bs2 all zero), the m=1/m=2 forms are exactly 0: reduced loop with
// 5 MFMA/chunk (b0 only), no M11 loads, vmcnt(0) barriers. Otherwise the
// proven full loop (15 MFMA, counted vmcnt(1)).
// ---------------------------------------------------------------------------
__global__ __launch_bounds__(NTD, 4) void kD(
    const unsigned int* __restrict__ A1u,
    const unsigned short* __restrict__ M11,
    const float* __restrict__ E, const float* __restrict__ tok,
    const int* __restrict__ h1, const int* __restrict__ h2,
    const int* __restrict__ s2,
    const float* __restrict__ Ws2, const float* __restrict__ bs2,
    const unsigned int* __restrict__ ZP, float* __restrict__ Q,
    const int* __restrict__ flagP)
{
    __shared__ __align__(16) unsigned int   ZPl[DD];           // 32768 B
    __shared__ __align__(16) unsigned short Lt[2][SROWS*32];   // 20480 B
    __shared__ __align__(16) unsigned int   Mt01[2][TND*M01W]; // 13824 B
    __shared__ unsigned short h1l[CC];                         //  1536 B

    const int bid = blockIdx.x;
    const int wg  = (bid & 7)*(NWGD/8) + (bid >> 3);
    const int b   = wg / NETD;
    const int et  = wg % NETD;
    const int tid = threadIdx.x;
    const int e0  = et * TND;
    const int fl  = *flagP;

    {
        const uint4* src = (const uint4*)(ZP + (size_t)b*DD);
        uint4* dst = (uint4*)ZPl;
        for (int i = tid; i < DD/4; i += NTD) dst[i] = src[i];
    }
    for (int c = tid; c < CC; c += NTD) h1l[c] = (unsigned short)h1[c];

    const int lane = tid & 63;
    const int wv   = tid >> 6;        // wave 0..5
    const int esub = wv % 3;          // e-sub-tile (16 cols)
    const int shf  = wv / 3;          // s-half
    const int l15  = lane & 15;
    const int l4   = lane >> 4;
    const int eg   = e0 + esub*16 + l15;

    int gh2[4];
    #pragma unroll
    for (int j = 0; j < 4; ++j) gh2[j] = h2[e0 + ((tid + j*NTD) >> 5)];
    __syncthreads();

    const char* Abase = (const char*)A1u + (size_t)b*NCKA*SROWS*64;

#define BARC() do { \
    asm volatile("s_waitcnt vmcnt(1) lgkmcnt(0)" ::: "memory"); \
    __builtin_amdgcn_sched_barrier(0); \
    __builtin_amdgcn_s_barrier(); \
    __builtin_amdgcn_sched_barrier(0); \
} while (0)

#define BARC0() do { \
    asm volatile("s_waitcnt vmcnt(0) lgkmcnt(0)" ::: "memory"); \
    __builtin_amdgcn_sched_barrier(0); \
    __builtin_amdgcn_s_barrier(); \
    __builtin_amdgcn_sched_barrier(0); \
} while (0)

#define STAGE_A(K, BUF) { \
    const char* cbase = Abase + (size_t)(K)*SROWS*64; \
    gload16(cbase + wv*1024 + lane*16, (char*)(BUF) + wv*1024); \
    if (wv < 4) \
        gload16(cbase + 6144 + wv*1024 + lane*16, \
                (char*)(BUF) + 6144 + wv*1024); \
    }

#define GATHER(K, MT) { \
    _Pragma("unroll") \
    for (int j = 0; j < 4; ++j) { \
        int idx = tid + j*NTD; \
        int ge = idx >> 5, gc = idx & 31; \
        int ad = ((int)h1l[(K)*32 + gc] + gh2[j]) & (DD-1); \
        MT[ge*M01W + gc] = ZPl[ad]; \
    } }

#define LOADB2(K) \
    (*(const short8*)&M11[((size_t)(K)*768 + eg)*32 + l4*8])

#define MFMA_STEP(LT, MT, BQ) { \
    const unsigned int* mp = &MT[(esub*16 + l15)*M01W + l4*8]; \
    uint4 p0 = *(const uint4*)mp; \
    uint4 p1 = *(const uint4*)(mp + 4); \
    union { unsigned int u[4]; short8 s; } b0, b1; \
    b0.u[0] = (p0.x & 0xffffu) | (p0.y << 16); \
    b1.u[0] = (p0.x >> 16)     | (p0.y & 0xffff0000u); \
    b0.u[1] = (p0.z & 0xffffu) | (p0.w << 16); \
    b1.u[1] = (p0.z >> 16)     | (p0.w & 0xffff0000u); \
    b0.u[2] = (p1.x & 0xffffu) | (p1.y << 16); \
    b1.u[2] = (p1.x >> 16)     | (p1.y & 0xffff0000u); \
    b0.u[3] = (p1.z & 0xffffu) | (p1.w << 16); \
    b1.u[3] = (p1.z >> 16)     | (p1.w & 0xffff0000u); \
    _Pragma("unroll") \
    for (int t = 0; t < 5; ++t) { \
        int R = shf*80 + t*16 + l15; \
        short8 af = *(const short8*)&LT[R*32 + ((l4 ^ (R & 3))*8)]; \
        acc0[t] = __builtin_amdgcn_mfma_f32_16x16x32_bf16(af, b0.s, acc0[t], 0,0,0); \
        acc1[t] = __builtin_amdgcn_mfma_f32_16x16x32_bf16(af, b1.s, acc1[t], 0,0,0); \
        acc2[t] = __builtin_amdgcn_mfma_f32_16x16x32_bf16(af, BQ,   acc2[t], 0,0,0); \
    } }

#define MFMA_STEP0(LT, MT) { \
    const unsigned int* mp = &MT[(esub*16 + l15)*M01W + l4*8]; \
    uint4 p0 = *(const uint4*)mp; \
    uint4 p1 = *(const uint4*)(mp + 4); \
    union { unsigned int u[4]; short8 s; } b0; \
    b0.u[0] = (p0.x & 0xffffu) | (p0.y << 16); \
    b0.u[1] = (p0.z & 0xffffu) | (p0.w << 16); \
    b0.u[2] = (p1.x & 0xffffu) | (p1.y << 16); \
    b0.u[3] = (p1.z & 0xffffu) | (p1.w << 16); \
    _Pragma("unroll") \
    for (int t = 0; t < 5; ++t) { \
        int R = shf*80 + t*16 + l15; \
        short8 af = *(const short8*)&LT[R*32 + ((l4 ^ (R & 3))*8)]; \
        acc0[t] = __builtin_amdgcn_mfma_f32_16x16x32_bf16(af, b0.s, acc0[t], 0,0,0); \
    } }

    f32x4 acc0[5], acc1[5], acc2[5];
    #pragma unroll
    for (int t = 0; t < 5; ++t) {
        acc0[t] = (f32x4){0.f,0.f,0.f,0.f};
        acc1[t] = (f32x4){0.f,0.f,0.f,0.f};
        acc2[t] = (f32x4){0.f,0.f,0.f,0.f};
    }

    if (fl) {
        short8 bqA, bqB;
        STAGE_A(0, Lt[0])
        GATHER(0, Mt01[0])
        __builtin_amdgcn_sched_barrier(0);
        bqA = LOADB2(0);
        BARC();

        #pragma unroll 1
        for (int k = 0; k < NCH; k += 2) {
            if (k + 1 < NCH) {
                STAGE_A(k + 1, Lt[1])
                GATHER(k + 1, Mt01[1])
                __builtin_amdgcn_sched_barrier(0);
                bqB = LOADB2(k + 1);
            }
            MFMA_STEP(Lt[0], Mt01[0], bqA)
            BARC();

            if (k + 2 < NCH) {
                STAGE_A(k + 2, Lt[0])
                GATHER(k + 2, Mt01[0])
                __builtin_amdgcn_sched_barrier(0);
                bqA = LOADB2(k + 2);
            }
            if (k + 1 < NCH) {
                MFMA_STEP(Lt[1], Mt01[1], bqB)
            }
            BARC();
        }
    } else {
        STAGE_A(0, Lt[0])
        GATHER(0, Mt01[0])
        BARC0();

        #pragma unroll 1
        for (int k = 0; k < NCH; k += 2) {
            if (k + 1 < NCH) {
                STAGE_A(k + 1, Lt[1])
                GATHER(k + 1, Mt01[1])
            }
            MFMA_STEP0(Lt[0], Mt01[0])
            BARC0();

            if (k + 2 < NCH) {
                STAGE_A(k + 2, Lt[0])
                GATHER(k + 2, Mt01[0])
            }
            if (k + 1 < NCH) {
                MFMA_STEP0(Lt[1], Mt01[1])
            }
            BARC0();
        }
    }
#undef BARC
#undef BARC0
#undef STAGE_A
#undef GATHER
#undef LOADB2
#undef MFMA_STEP
#undef MFMA_STEP0

    // --- epilogue: combine 3 forms (acc1/acc2 zero on reduced path),
    //     reduce 16 e-lanes, one atomic ---
    const float s2e = (float)s2[eg];
    const float t2e = tok[CC + eg] * s2e;
    #pragma unroll
    for (int t = 0; t < 5; ++t) {
        #pragma unroll
        for (int rr = 0; rr < 4; ++rr) {
            int s = shf*80 + t*16 + l4*4 + rr;
            float qv = 0.f;
            if (s < SS) {
                float a2v = E[((size_t)b*SS + s)*CC + eg] * s2e + t2e;
                float w2v = Ws2[s], bbv = bs2[s];
                qv = (w2v*w2v*acc0[t][rr] + w2v*bbv*acc1[t][rr]
                      + bbv*bbv*acc2[t][rr]) * a2v;
            }
            qv += __shfl_xor(qv, 1);
            qv += __shfl_xor(qv, 2);
            qv += __shfl_xor(qv, 4);
            qv += __shfl_xor(qv, 8);
            if (l15 == 0 && s < SS)
                unsafeAtomicAdd(&Q[b*SS + s], qv);
        }
    }
}

// ---------------------------------------------------------------------------
// kE: bp = sign(Q)*sqrt(|Q|+1e-5); L2-normalize over s; project W_out.
// ---------------------------------------------------------------------------
__global__ __launch_bounds__(256) void kE(
    const float* __restrict__ Q, const float* __restrict__ Wout,
    const float* __restrict__ bout, float* __restrict__ out)
{
    __shared__ float red[8];
    const int b = blockIdx.x, tid = threadIdx.x;
    float v = 0.f, w = 0.f;
    if (tid < SS) {
        float ip = Q[b*SS + tid];
        float sg = (ip > 0.f) ? 1.f : ((ip < 0.f) ? -1.f : 0.f);
        v = sg * sqrtf(fabsf(ip) + 1e-5f);
        w = v * Wout[tid];
    }
    float sq = v * v;
    #pragma unroll
    for (int off = 32; off > 0; off >>= 1) {
        sq += __shfl_down(sq, off, 64);
        w  += __shfl_down(w,  off, 64);
    }
    if ((tid & 63) == 0) { red[tid >> 6] = sq; red[4 + (tid >> 6)] = w; }
    __syncthreads();
    if (tid == 0) {
        float ssq  = red[0] + red[1] + red[2] + red[3];
        float sw   = red[4] + red[5] + red[6] + red[7];
        float norm = fmaxf(sqrtf(ssq), 1e-12f);
        out[b] = sw / norm + bout[0];
    }
}

// ---------------------------------------------------------------------------
extern "C" void kernel_launch(void* const* d_in, const int* in_sizes, int n_in,
                              void* d_out, int out_size, void* d_ws, size_t ws_size,
                              hipStream_t stream) {
    const float* sensor = (const float*)d_in[0];
    const float* E      = (const float*)d_in[1];
    const int*   h1     = (const int*)d_in[3];
    const int*   h2     = (const int*)d_in[4];
    const int*   s1     = (const int*)d_in[5];
    const int*   s2     = (const int*)d_in[6];
    const float* Wsen   = (const float*)d_in[8];
    const float* bsen   = (const float*)d_in[9];
    const float* Ws2    = (const float*)d_in[10];
    const float* bs2    = (const float*)d_in[11];
    const float* Wout   = (const float*)d_in[12];
    const float* bout   = (const float*)d_in[13];
    const float* tok    = (const float*)d_in[14];
    float* out = (float*)d_out;

    char* ws = (char*)d_ws;
    const size_t SZ_CTG  = (size_t)BB*CC*16;        //   393,216
    const size_t SZ_P2G  = (size_t)BB*DD*8;         // 2,097,152
    const size_t SZ_ZP   = (size_t)BB*DD*4;         // 1,048,576
    const size_t SZ_Z11  = (size_t)DD*2;            //    16,384
    const size_t SZ_M11  = (size_t)NCKA*768*64;     // 1,179,648
    const size_t SZ_Q    = (size_t)BB*SS*4;         //    18,560
    const size_t SZ_FLAG = 64;
    const size_t SZ_A1   = (size_t)BB*NCKA*SROWS*64;// 7,864,320
    const size_t needFused =
        SZ_CTG+SZ_P2G+SZ_ZP+SZ_Z11+SZ_M11+SZ_Q+SZ_FLAG+SZ_A1;

    if (ws_size >= needFused) {
        // ---- fused path: A1u non-aliased, kA runs concurrently with kS ----
        float4* CTG = (float4*)ws;
        float2* P2G = (float2*)(ws + SZ_CTG);
        unsigned int*   ZP   = (unsigned int*)(ws + SZ_CTG + SZ_P2G);
        unsigned short* Z11b = (unsigned short*)((char*)ZP + SZ_ZP);
        unsigned int*   M11u = (unsigned int*)((char*)Z11b + SZ_Z11);
        float*          Q    = (float*)((char*)M11u + SZ_M11);
        int*            flagP= (int*)((char*)Q + SZ_Q);
        unsigned int*   A1u  = (unsigned int*)((char*)flagP + SZ_FLAG);

        kSA<<<dim3(352), dim3(512), 0, stream>>>(
            sensor, Wsen, bsen, h1, h2, s1, s2, CTG, P2G, E, tok, A1u, Q);
        kZ<<<dim3(BB*NSL), dim3(ZT), 0, stream>>>(
            CTG, P2G, ZP, Z11b, bs2, flagP);
        kM11<<<dim3(NCKA), dim3(512), 0, stream>>>(Z11b, h1, h2, M11u, flagP);
        kD<<<dim3(NWGD), dim3(NTD), 0, stream>>>(
            A1u, (const unsigned short*)M11u, E, tok, h1, h2, s2,
            Ws2, bs2, ZP, Q, flagP);
        kE<<<dim3(BB), dim3(256), 0, stream>>>(Q, Wout, bout, out);
    } else {
        // ---- fallback: A1u aliases CTG/P2G after kZ ----
        float4* CTG = (float4*)ws;
        float2* P2G = (float2*)(ws + SZ_CTG);
        unsigned int* A1u = (unsigned int*)ws;
        unsigned int*   ZP   = (unsigned int*)(ws + SZ_A1);
        unsigned short* Z11b = (unsigned short*)(ws + SZ_A1 + SZ_ZP);
        unsigned int*   M11u = (unsigned int*)((char*)Z11b + SZ_Z11);
        float* Q = (float*)((char*)M11u + SZ_M11);
        int*   flagP = (int*)((char*)Q + SZ_Q);

        hipMemsetAsync(Q, 0, SZ_Q, stream);
        kS<<<dim3(BB), dim3(512), 0, stream>>>(
            sensor, Wsen, bsen, h1, h2, s1, s2, CTG, P2G);
        kZ<<<dim3(BB*NSL), dim3(ZT), 0, stream>>>(
            CTG, P2G, ZP, Z11b, bs2, flagP);
        kAM<<<dim3(344), dim3(512), 0, stream>>>(
            E, tok, s1, A1u, Z11b, h1, h2, M11u, flagP);
        kD<<<dim3(NWGD), dim3(NTD), 0, stream>>>(
            A1u, (const unsigned short*)M11u, E, tok, h1, h2, s2,
            Ws2, bs2, ZP, Q, flagP);
        kE<<<dim3(BB), dim3(256), 0, stream>>>(Q, Wout, bout, out);
    }
}

// Round 26
// 140.508 us; speedup vs baseline: 1.1991x; 1.0039x over previous
//
#include <hip/hip_runtime.h>
#include <hip/hip_bf16.h>
#include <math.h>

#define DD 8192     // sketch dimension d
#define CC 768      // channels
#define SS 145      // sequence length
#define BB 32       // batch
#define SN 64       // sensor dim
#define SROWS 160   // padded s rows (10 tiles of 16)
#define NCKA 24     // A1u chunks (32 c each)

// ---- kD geometry: grid EXACTLY 512 = 2 blocks/CU x 256 CU (no tail) ----
#define NETD 16          // e-tiles of 48
#define TND 48           // e-cols per block
#define NCH 24           // chunks per block (all 768 c)
#define M01W 36          // Mt01 row stride in u32 (144 B)
#define NTD 384          // 6 waves = 3 e-subs x 2 s-halves
#define NWGD (BB*NETD)   // 512 blocks

// ---- kZ geometry ----
#define ZT 512
#define NSL 16

typedef __attribute__((ext_vector_type(8))) short short8;   // 8 bf16
typedef __attribute__((ext_vector_type(4))) float f32x4;    // MFMA acc
typedef __attribute__((ext_vector_type(2))) float f32x2;    // packed fp32

__device__ __forceinline__ void gload16(const void* g, void* l) {
    __builtin_amdgcn_global_load_lds(
        (const __attribute__((address_space(1))) unsigned int*)g,
        (__attribute__((address_space(3))) unsigned int*)l, 16, 0, 0);
}

// ---------------------------------------------------------------------------
// kS body: per-b sketch build. u[b,c]=b_sen[c]+sensor·Wsen[c,:];
// CTG[b][c]=(u1, s1, bits(h1c*8), 0)  [h1 pre-scaled to float2-BYTE offset];
// P2G[b][t]=(S2u_b[t], S2s[t]) fp32 pairs.
// ---------------------------------------------------------------------------
__device__ __forceinline__ void kS_body(
    int b, int tid,
    const float* __restrict__ sensor, const float* __restrict__ Wsen,
    const float* __restrict__ bsen,
    const int* __restrict__ h1, const int* __restrict__ h2,
    const int* __restrict__ s1, const int* __restrict__ s2,
    float4* __restrict__ CTG, float2* __restrict__ P2G, float2* P2l,
    float* sens)
{
    if (tid < SN) sens[tid] = sensor[b*SN + tid];
    {
        float4* p4 = (float4*)P2l;
        #pragma unroll
        for (int i = 0; i < 8; ++i) p4[tid + i*512] = make_float4(0.f,0.f,0.f,0.f);
    }
    __syncthreads();

    for (int c = tid; c < CC; c += 512) {
        float u = bsen[c];
        const float4* w = (const float4*)(Wsen + (size_t)c*SN);
        #pragma unroll
        for (int n4 = 0; n4 < 16; ++n4) {
            float4 wv = w[n4];
            u += sens[4*n4+0]*wv.x + sens[4*n4+1]*wv.y
               + sens[4*n4+2]*wv.z + sens[4*n4+3]*wv.w;
        }
        float f1 = (float)s1[c], f2 = (float)s2[c];
        float4 ct;
        ct.x = u * f1; ct.y = f1; ct.z = __int_as_float(h1[c] << 3); ct.w = 0.f;
        CTG[(size_t)b*CC + c] = ct;
        int t = h2[c];
        unsafeAtomicAdd(&P2l[t].x, u * f2);
        unsafeAtomicAdd(&P2l[t].y, f2);
    }
    __syncthreads();

    {
        const float4* p4 = (const float4*)P2l;
        float4* dst = (float4*)(P2G + (size_t)b*DD);
        #pragma unroll
        for (int i = 0; i < 8; ++i) dst[tid + i*512] = p4[tid + i*512];
    }
}

__device__ __forceinline__ void kA_body(
    int bid, int tid,
    const float* __restrict__ E, const float* __restrict__ tok,
    const int* __restrict__ s1, unsigned int* __restrict__ A1u)
{
    if (tid >= 384) return;
    const int b  = bid / 10;
    const int r0 = (bid % 10) * 16;
    const int c  = 2*tid;
    const int ck = tid >> 4;
    const int c2 = tid & 15;
    const float s1a = (float)s1[c], s1b = (float)s1[c+1];
    const float ta = tok[CC + c] * s1a, tb = tok[CC + c + 1] * s1b;
    #pragma unroll
    for (int rr = 0; rr < 16; ++rr) {
        int row = r0 + rr;
        unsigned int word = 0;
        if (row < SS) {
            float2 ev = *(const float2*)&E[((size_t)b*SS + row)*CC + c];
            __hip_bfloat16 x0 = __float2bfloat16(ev.x*s1a + ta);
            __hip_bfloat16 x1 = __float2bfloat16(ev.y*s1b + tb);
            word = (unsigned int)*(unsigned short*)&x0
                 | ((unsigned int)*(unsigned short*)&x1 << 16);
        }
        int gp = (c2 >> 2) ^ (row & 3);
        A1u[((size_t)(b*NCKA + ck)*SROWS + row)*16 + gp*4 + (c2 & 3)] = word;
    }
}

// ---------------------------------------------------------------------------
// kSA (fused path): blocks [0,320) build A1u; [320,352) per-b sketch (kS);
// block 320 also zeroes Q.
// ---------------------------------------------------------------------------
__global__ __launch_bounds__(512) void kSA(
    const float* __restrict__ sensor, const float* __restrict__ Wsen,
    const float* __restrict__ bsen,
    const int* __restrict__ h1, const int* __restrict__ h2,
    const int* __restrict__ s1, const int* __restrict__ s2,
    float4* __restrict__ CTG, float2* __restrict__ P2G,
    const float* __restrict__ E, const float* __restrict__ tok,
    unsigned int* __restrict__ A1u, float* __restrict__ Q)
{
    __shared__ float2 P2l[DD];
    __shared__ float  sens[SN];
    const int bid = blockIdx.x;
    const int tid = threadIdx.x;
    if (bid < 320) {
        kA_body(bid, tid, E, tok, s1, A1u);
    } else {
        if (bid == 320) for (int i = tid; i < BB*SS; i += 512) Q[i] = 0.f;
        kS_body(bid - 320, tid, sensor, Wsen, bsen, h1, h2, s1, s2,
                CTG, P2G, P2l, sens);
    }
}

// kS standalone (fallback path)
__global__ __launch_bounds__(512) void kS(
    const float* __restrict__ sensor, const float* __restrict__ Wsen,
    const float* __restrict__ bsen,
    const int* __restrict__ h1, const int* __restrict__ h2,
    const int* __restrict__ s1, const int* __restrict__ s2,
    float4* __restrict__ CTG, float2* __restrict__ P2G)
{
    __shared__ float2 P2l[DD];
    __shared__ float  sens[SN];
    kS_body(blockIdx.x, threadIdx.x, sensor, Wsen, bsen, h1, h2, s1, s2,
            CTG, P2G, P2l, sens);
}

// ---------------------------------------------------------------------------
// kZ v7: v3 + CT table staged in LDS (12 KB, broadcast ds_read_b128).
// Rationale: v3's uniform ctp[c] reads were s_load (SMEM), which shares
// lgkmcnt with ds_read and returns OUT-OF-ORDER -- every gather-use wait
// conservatively drains pending s_loads, throttling LDS pipelining. With
// CT in LDS the inner loop is DS-only: in-order returns, precise counted
// lgkmcnt, deep gather pipeline. Uniform-address ds_read broadcasts (no
// conflict, no traffic amplification -- unlike v6's per-lane VMEM).
// Also (bid==0,tid==0) writes flagP[0] = any(bs2 != 0).
// Writes ZP[b][d]=pack(bf16 Zuu,bf16 Zcr); b==0 also Z11b.
// ---------------------------------------------------------------------------
__global__ __launch_bounds__(ZT) void kZ(
    const float4* __restrict__ CTG, const float2* __restrict__ P2G,
    unsigned int* __restrict__ ZP, unsigned short* __restrict__ Z11b,
    const float* __restrict__ bs2, int* __restrict__ flagP)
{
    __shared__ float2 P2l[DD];        // 65536 B
    __shared__ float4 CTl[CC];        // 12288 B -> total 77.8 KB, 2 blocks/CU

    const int bid = blockIdx.x;
    const int wg  = (bid & 7)*(BB*NSL/8) + (bid >> 3);
    const int b   = wg >> 4;
    const int dsl = wg & (NSL-1);
    const int tid = threadIdx.x;
    const bool doZ11 = (b == 0);

    if (bid == 0 && tid == 0) {
        int f = 0;
        for (int s = 0; s < SS; ++s) f |= (bs2[s] != 0.f) ? 1 : 0;
        *flagP = f;
    }

    {
        const float4* src = (const float4*)(P2G + (size_t)b*DD);
        float4* dst = (float4*)P2l;
        #pragma unroll
        for (int i = 0; i < 8; ++i) dst[tid + i*ZT] = src[tid + i*ZT];
    }
    {
        const float4* csrc = CTG + (size_t)b*CC;
        CTl[tid] = csrc[tid];
        if (tid < CC - ZT) CTl[ZT + tid] = csrc[ZT + tid];
    }
    __syncthreads();

    const int d  = dsl*ZT + tid;
    const int d8 = d << 3;                     // byte offset of own float2
    f32x2 accP = {0.f, 0.f};                   // (accU, accC_a)
    float accC2 = 0.f, acc1 = 0.f;
    #pragma unroll 4
    for (int c = 0; c < CC; ++c) {
        float4 ct = CTl[c];                    // broadcast ds_read_b128
        int ab = (d8 - __float_as_int(ct.z)) & 65535;   // ((d-h1c)&8191)*8
        f32x2 p = *(const f32x2*)((const char*)P2l + ab);
        f32x2 uu = {ct.x, ct.x};
        accP = __builtin_elementwise_fma(uu, p, accP);  // v_pk_fma_f32
        accC2 = fmaf(ct.y, p.x, accC2);
        if (doZ11) acc1 = fmaf(ct.y, p.y, acc1);
    }
    float accU = accP.x, accC = accP.y + accC2;

    __hip_bfloat16 zu = __float2bfloat16(accU);
    __hip_bfloat16 zc = __float2bfloat16(accC);
    ZP[(size_t)b*DD + d] = (unsigned int)*(unsigned short*)&zu
                         | ((unsigned int)*(unsigned short*)&zc << 16);
    if (doZ11) {
        __hip_bfloat16 z1 = __float2bfloat16(acc1);
        Z11b[d] = *(unsigned short*)&z1;
    }
}

// ---------------------------------------------------------------------------
// kM11: materialize b-independent m=2 matrix (24 blocks). Skipped entirely
// when bs2 == 0 (M11 is then multiplied by bb^2 = 0 and never read).
// ---------------------------------------------------------------------------
__global__ __launch_bounds__(512) void kM11(
    const unsigned short* __restrict__ Z11b,
    const int* __restrict__ h1, const int* __restrict__ h2,
    unsigned int* __restrict__ M11u, const int* __restrict__ flagP)
{
    __shared__ unsigned short Z11l[DD];
    if (*flagP == 0) return;
    const int ck  = blockIdx.x;
    const int tid = threadIdx.x;
    {
        const uint4* src = (const uint4*)Z11b;
        uint4* dst = (uint4*)Z11l;
        #pragma unroll
        for (int i = 0; i < 2; ++i) dst[tid + i*512] = src[tid + i*512];
    }
    __syncthreads();

    #pragma unroll 4
    for (int i = 0; i < 24; ++i) {
        int idx = tid + i*512;
        int ep  = idx >> 4;
        int cpp = idx & 15;
        int ha = h1[ck*32 + 2*cpp];
        int hb = h1[ck*32 + 2*cpp + 1];
        int he = h2[ep];
        unsigned int lo = Z11l[(ha + he) & (DD-1)];
        unsigned int hi = Z11l[(hb + he) & (DD-1)];
        M11u[((size_t)ck*768 + ep)*16 + cpp] = lo | (hi << 16);
    }
}

// kAM (fallback path): kA + kM11 fused; kM11 part honors the flag.
__global__ __launch_bounds__(512) void kAM(
    const float* __restrict__ E, const float* __restrict__ tok,
    const int* __restrict__ s1, unsigned int* __restrict__ A1u,
    const unsigned short* __restrict__ Z11b,
    const int* __restrict__ h1, const int* __restrict__ h2,
    unsigned int* __restrict__ M11u, const int* __restrict__ flagP)
{
    __shared__ unsigned short Z11l[DD];
    const int bid = blockIdx.x;
    const int tid = threadIdx.x;
    if (bid < 320) {
        kA_body(bid, tid, E, tok, s1, A1u);
    } else {
        if (*flagP == 0) return;
        const int ck = bid - 320;
        {
            const uint4* src = (const uint4*)Z11b;
            uint4* dst = (uint4*)Z11l;
            #pragma unroll
            for (int i = 0; i < 2; ++i) dst[tid + i*512] = src[tid + i*512];
        }
        __syncthreads();
        #pragma unroll 4
        for (int i = 0; i < 24; ++i) {
            int idx = tid + i*512;
            int ep  = idx >> 4;
            int cpp = idx & 15;
            int ha = h1[ck*32 + 2*cpp];
            int hb = h1[ck*32 + 2*cpp + 1];
            int he = h2[ep];
            unsigned int lo = Z11l[(ha + he) & (DD-1)];
            unsigned int hi = Z11l[(hb + he) & (DD-1)];
            M11u[((size_t)ck*768 + ep)*16 + cpp] = lo | (hi << 16);
        }
    }
}

// ---------------------------------------------------------------------------
// kD: fused 3-form MFMA; grid 512 no-tail, dbuf Lt/Mt01. When flag==0
// (bs2 all zero), the m=1/m=2 forms are exactly 0: reduced loop with
// 5 MFMA/chunk (b0 only), no M11 loads, vmcnt(0) barriers. Otherwise the
// proven full loop (15 MFMA, counted vmcnt(1)).
// ---------------------------------------------------------------------------
__global__ __launch_bounds__(NTD, 4) void kD(
    const unsigned int* __restrict__ A1u,
    const unsigned short* __restrict__ M11,
    const float* __restrict__ E, const float* __restrict__ tok,
    const int* __restrict__ h1, const int* __restrict__ h2,
    const int* __restrict__ s2,
    const float* __restrict__ Ws2, const float* __restrict__ bs2,
    const unsigned int* __restrict__ ZP, float* __restrict__ Q,
    const int* __restrict__ flagP)
{
    __shared__ __align__(16) unsigned int   ZPl[DD];           // 32768 B
    __shared__ __align__(16) unsigned short Lt[2][SROWS*32];   // 20480 B
    __shared__ __align__(16) unsigned int   Mt01[2][TND*M01W]; // 13824 B
    __shared__ unsigned short h1l[CC];                         //  1536 B

    const int bid = blockIdx.x;
    const int wg  = (bid & 7)*(NWGD/8) + (bid >> 3);
    const int b   = wg / NETD;
    const int et  = wg % NETD;
    const int tid = threadIdx.x;
    const int e0  = et * TND;
    const int fl  = *flagP;

    {
        const uint4* src = (const uint4*)(ZP + (size_t)b*DD);
        uint4* dst = (uint4*)ZPl;
        for (int i = tid; i < DD/4; i += NTD) dst[i] = src[i];
    }
    for (int c = tid; c < CC; c += NTD) h1l[c] = (unsigned short)h1[c];

    const int lane = tid & 63;
    const int wv   = tid >> 6;        // wave 0..5
    const int esub = wv % 3;          // e-sub-tile (16 cols)
    const int shf  = wv / 3;          // s-half
    const int l15  = lane & 15;
    const int l4   = lane >> 4;
    const int eg   = e0 + esub*16 + l15;

    int gh2[4];
    #pragma unroll
    for (int j = 0; j < 4; ++j) gh2[j] = h2[e0 + ((tid + j*NTD) >> 5)];
    __syncthreads();

    const char* Abase = (const char*)A1u + (size_t)b*NCKA*SROWS*64;

#define BARC() do { \
    asm volatile("s_waitcnt vmcnt(1) lgkmcnt(0)" ::: "memory"); \
    __builtin_amdgcn_sched_barrier(0); \
    __builtin_amdgcn_s_barrier(); \
    __builtin_amdgcn_sched_barrier(0); \
} while (0)

#define BARC0() do { \
    asm volatile("s_waitcnt vmcnt(0) lgkmcnt(0)" ::: "memory"); \
    __builtin_amdgcn_sched_barrier(0); \
    __builtin_amdgcn_s_barrier(); \
    __builtin_amdgcn_sched_barrier(0); \
} while (0)

#define STAGE_A(K, BUF) { \
    const char* cbase = Abase + (size_t)(K)*SROWS*64; \
    gload16(cbase + wv*1024 + lane*16, (char*)(BUF) + wv*1024); \
    if (wv < 4) \
        gload16(cbase + 6144 + wv*1024 + lane*16, \
                (char*)(BUF) + 6144 + wv*1024); \
    }

#define GATHER(K, MT) { \
    _Pragma("unroll") \
    for (int j = 0; j < 4; ++j) { \
        int idx = tid + j*NTD; \
        int ge = idx >> 5, gc = idx & 31; \
        int ad = ((int)h1l[(K)*32 + gc] + gh2[j]) & (DD-1); \
        MT[ge*M01W + gc] = ZPl[ad]; \
    } }

#define LOADB2(K) \
    (*(const short8*)&M11[((size_t)(K)*768 + eg)*32 + l4*8])

#define MFMA_STEP(LT, MT, BQ) { \
    const unsigned int* mp = &MT[(esub*16 + l15)*M01W + l4*8]; \
    uint4 p0 = *(const uint4*)mp; \
    uint4 p1 = *(const uint4*)(mp + 4); \
    union { unsigned int u[4]; short8 s; } b0, b1; \
    b0.u[0] = (p0.x & 0xffffu) | (p0.y << 16); \
    b1.u[0] = (p0.x >> 16)     | (p0.y & 0xffff0000u); \
    b0.u[1] = (p0.z & 0xffffu) | (p0.w << 16); \
    b1.u[1] = (p0.z >> 16)     | (p0.w & 0xffff0000u); \
    b0.u[2] = (p1.x & 0xffffu) | (p1.y << 16); \
    b1.u[2] = (p1.x >> 16)     | (p1.y & 0xffff0000u); \
    b0.u[3] = (p1.z & 0xffffu) | (p1.w << 16); \
    b1.u[3] = (p1.z >> 16)     | (p1.w & 0xffff0000u); \
    _Pragma("unroll") \
    for (int t = 0; t < 5; ++t) { \
        int R = shf*80 + t*16 + l15; \
        short8 af = *(const short8*)&LT[R*32 + ((l4 ^ (R & 3))*8)]; \
        acc0[t] = __builtin_amdgcn_mfma_f32_16x16x32_bf16(af, b0.s, acc0[t], 0,0,0); \
        acc1[t] = __builtin_amdgcn_mfma_f32_16x16x32_bf16(af, b1.s, acc1[t], 0,0,0); \
        acc2[t] = __builtin_amdgcn_mfma_f32_16x16x32_bf16(af, BQ,   acc2[t], 0,0,0); \
    } }

#define MFMA_STEP0(LT, MT) { \
    const unsigned int* mp = &MT[(esub*16 + l15)*M01W + l4*8]; \
    uint4 p0 = *(const uint4*)mp; \
    uint4 p1 = *(const uint4*)(mp + 4); \
    union { unsigned int u[4]; short8 s; } b0; \
    b0.u[0] = (p0.x & 0xffffu) | (p0.y << 16); \
    b0.u[1] = (p0.z & 0xffffu) | (p0.w << 16); \
    b0.u[2] = (p1.x & 0xffffu) | (p1.y << 16); \
    b0.u[3] = (p1.z & 0xffffu) | (p1.w << 16); \
    _Pragma("unroll") \
    for (int t = 0; t < 5; ++t) { \
        int R = shf*80 + t*16 + l15; \
        short8 af = *(const short8*)&LT[R*32 + ((l4 ^ (R & 3))*8)]; \
        acc0[t] = __builtin_amdgcn_mfma_f32_16x16x32_bf16(af, b0.s, acc0[t], 0,0,0); \
    } }

    f32x4 acc0[5], acc1[5], acc2[5];
    #pragma unroll
    for (int t = 0; t < 5; ++t) {
        acc0[t] = (f32x4){0.f,0.f,0.f,0.f};
        acc1[t] = (f32x4){0.f,0.f,0.f,0.f};
        acc2[t] = (f32x4){0.f,0.f,0.f,0.f};
    }

    if (fl) {
        short8 bqA, bqB;
        STAGE_A(0, Lt[0])
        GATHER(0, Mt01[0])
        __builtin_amdgcn_sched_barrier(0);
        bqA = LOADB2(0);
        BARC();

        #pragma unroll 1
        for (int k = 0; k < NCH; k += 2) {
            if (k + 1 < NCH) {
                STAGE_A(k + 1, Lt[1])
                GATHER(k + 1, Mt01[1])
                __builtin_amdgcn_sched_barrier(0);
                bqB = LOADB2(k + 1);
            }
            MFMA_STEP(Lt[0], Mt01[0], bqA)
            BARC();

            if (k + 2 < NCH) {
                STAGE_A(k + 2, Lt[0])
                GATHER(k + 2, Mt01[0])
                __builtin_amdgcn_sched_barrier(0);
                bqA = LOADB2(k + 2);
            }
            if (k + 1 < NCH) {
                MFMA_STEP(Lt[1], Mt01[1], bqB)
            }
            BARC();
        }
    } else {
        STAGE_A(0, Lt[0])
        GATHER(0, Mt01[0])
        BARC0();

        #pragma unroll 1
        for (int k = 0; k < NCH; k += 2) {
            if (k + 1 < NCH) {
                STAGE_A(k + 1, Lt[1])
                GATHER(k + 1, Mt01[1])
            }
            MFMA_STEP0(Lt[0], Mt01[0])
            BARC0();

            if (k + 2 < NCH) {
                STAGE_A(k + 2, Lt[0])
                GATHER(k + 2, Mt01[0])
            }
            if (k + 1 < NCH) {
                MFMA_STEP0(Lt[1], Mt01[1])
            }
            BARC0();
        }
    }
#undef BARC
#undef BARC0
#undef STAGE_A
#undef GATHER
#undef LOADB2
#undef MFMA_STEP
#undef MFMA_STEP0

    // --- epilogue: combine 3 forms (acc1/acc2 zero on reduced path),
    //     reduce 16 e-lanes, one atomic ---
    const float s2e = (float)s2[eg];
    const float t2e = tok[CC + eg] * s2e;
    #pragma unroll
    for (int t = 0; t < 5; ++t) {
        #pragma unroll
        for (int rr = 0; rr < 4; ++rr) {
            int s = shf*80 + t*16 + l4*4 + rr;
            float qv = 0.f;
            if (s < SS) {
                float a2v = E[((size_t)b*SS + s)*CC + eg] * s2e + t2e;
                float w2v = Ws2[s], bbv = bs2[s];
                qv = (w2v*w2v*acc0[t][rr] + w2v*bbv*acc1[t][rr]
                      + bbv*bbv*acc2[t][rr]) * a2v;
            }
            qv += __shfl_xor(qv, 1);
            qv += __shfl_xor(qv, 2);
            qv += __shfl_xor(qv, 4);
            qv += __shfl_xor(qv, 8);
            if (l15 == 0 && s < SS)
                unsafeAtomicAdd(&Q[b*SS + s], qv);
        }
    }
}

// ---------------------------------------------------------------------------
// kE: bp = sign(Q)*sqrt(|Q|+1e-5); L2-normalize over s; project W_out.
// ---------------------------------------------------------------------------
__global__ __launch_bounds__(256) void kE(
    const float* __restrict__ Q, const float* __restrict__ Wout,
    const float* __restrict__ bout, float* __restrict__ out)
{
    __shared__ float red[8];
    const int b = blockIdx.x, tid = threadIdx.x;
    float v = 0.f, w = 0.f;
    if (tid < SS) {
        float ip = Q[b*SS + tid];
        float sg = (ip > 0.f) ? 1.f : ((ip < 0.f) ? -1.f : 0.f);
        v = sg * sqrtf(fabsf(ip) + 1e-5f);
        w = v * Wout[tid];
    }
    float sq = v * v;
    #pragma unroll
    for (int off = 32; off > 0; off >>= 1) {
        sq += __shfl_down(sq, off, 64);
        w  += __shfl_down(w,  off, 64);
    }
    if ((tid & 63) == 0) { red[tid >> 6] = sq; red[4 + (tid >> 6)] = w; }
    __syncthreads();
    if (tid == 0) {
        float ssq  = red[0] + red[1] + red[2] + red[3];
        float sw   = red[4] + red[5] + red[6] + red[7];
        float norm = fmaxf(sqrtf(ssq), 1e-12f);
        out[b] = sw / norm + bout[0];
    }
}

// ---------------------------------------------------------------------------
extern "C" void kernel_launch(void* const* d_in, const int* in_sizes, int n_in,
                              void* d_out, int out_size, void* d_ws, size_t ws_size,
                              hipStream_t stream) {
    const float* sensor = (const float*)d_in[0];
    const float* E      = (const float*)d_in[1];
    const int*   h1     = (const int*)d_in[3];
    const int*   h2     = (const int*)d_in[4];
    const int*   s1     = (const int*)d_in[5];
    const int*   s2     = (const int*)d_in[6];
    const float* Wsen   = (const float*)d_in[8];
    const float* bsen   = (const float*)d_in[9];
    const float* Ws2    = (const float*)d_in[10];
    const float* bs2    = (const float*)d_in[11];
    const float* Wout   = (const float*)d_in[12];
    const float* bout   = (const float*)d_in[13];
    const float* tok    = (const float*)d_in[14];
    float* out = (float*)d_out;

    char* ws = (char*)d_ws;
    const size_t SZ_CTG  = (size_t)BB*CC*16;        //   393,216
    const size_t SZ_P2G  = (size_t)BB*DD*8;         // 2,097,152
    const size_t SZ_ZP   = (size_t)BB*DD*4;         // 1,048,576
    const size_t SZ_Z11  = (size_t)DD*2;            //    16,384
    const size_t SZ_M11  = (size_t)NCKA*768*64;     // 1,179,648
    const size_t SZ_Q    = (size_t)BB*SS*4;         //    18,560
    const size_t SZ_FLAG = 64;
    const size_t SZ_A1   = (size_t)BB*NCKA*SROWS*64;// 7,864,320
    const size_t needFused =
        SZ_CTG+SZ_P2G+SZ_ZP+SZ_Z11+SZ_M11+SZ_Q+SZ_FLAG+SZ_A1;

    if (ws_size >= needFused) {
        // ---- fused path: A1u non-aliased, kA runs concurrently with kS ----
        float4* CTG = (float4*)ws;
        float2* P2G = (float2*)(ws + SZ_CTG);
        unsigned int*   ZP   = (unsigned int*)(ws + SZ_CTG + SZ_P2G);
        unsigned short* Z11b = (unsigned short*)((char*)ZP + SZ_ZP);
        unsigned int*   M11u = (unsigned int*)((char*)Z11b + SZ_Z11);
        float*          Q    = (float*)((char*)M11u + SZ_M11);
        int*            flagP= (int*)((char*)Q + SZ_Q);
        unsigned int*   A1u  = (unsigned int*)((char*)flagP + SZ_FLAG);

        kSA<<<dim3(352), dim3(512), 0, stream>>>(
            sensor, Wsen, bsen, h1, h2, s1, s2, CTG, P2G, E, tok, A1u, Q);
        kZ<<<dim3(BB*NSL), dim3(ZT), 0, stream>>>(
            CTG, P2G, ZP, Z11b, bs2, flagP);
        kM11<<<dim3(NCKA), dim3(512), 0, stream>>>(Z11b, h1, h2, M11u, flagP);
        kD<<<dim3(NWGD), dim3(NTD), 0, stream>>>(
            A1u, (const unsigned short*)M11u, E, tok, h1, h2, s2,
            Ws2, bs2, ZP, Q, flagP);
        kE<<<dim3(BB), dim3(256), 0, stream>>>(Q, Wout, bout, out);
    } else {
        // ---- fallback: A1u aliases CTG/P2G after kZ ----
        float4* CTG = (float4*)ws;
        float2* P2G = (float2*)(ws + SZ_CTG);
        unsigned int* A1u = (unsigned int*)ws;
        unsigned int*   ZP   = (unsigned int*)(ws + SZ_A1);
        unsigned short* Z11b = (unsigned short*)(ws + SZ_A1 + SZ_ZP);
        unsigned int*   M11u = (unsigned int*)((char*)Z11b + SZ_Z11);
        float* Q = (float*)((char*)M11u + SZ_M11);
        int*   flagP = (int*)((char*)Q + SZ_Q);

        hipMemsetAsync(Q, 0, SZ_Q, stream);
        kS<<<dim3(BB), dim3(512), 0, stream>>>(
            sensor, Wsen, bsen, h1, h2, s1, s2, CTG, P2G);
        kZ<<<dim3(BB*NSL), dim3(ZT), 0, stream>>>(
            CTG, P2G, ZP, Z11b, bs2, flagP);
        kAM<<<dim3(344), dim3(512), 0, stream>>>(
            E, tok, s1, A1u, Z11b, h1, h2, M11u, flagP);
        kD<<<dim3(NWGD), dim3(NTD), 0, stream>>>(
            A1u, (const unsigned short*)M11u, E, tok, h1, h2, s2,
            Ws2, bs2, ZP, Q, flagP);
        kE<<<dim3(BB), dim3(256), 0, stream>>>(Q, Wout, bout, out);
    }
}

// Round 27
// 140.206 us; speedup vs baseline: 1.2017x; 1.0022x over previous
//
#include <hip/hip_runtime.h>
#include <hip/hip_bf16.h>
#include <math.h>

#define DD 8192     // sketch dimension d
#define CC 768      // channels
#define SS 145      // sequence length
#define BB 32       // batch
#define SN 64       // sensor dim
#define SROWS 160   // padded s rows (10 tiles of 16)
#define NCKA 24     // A1u chunks (32 c each)

// ---- kD geometry: grid EXACTLY 512 = 2 blocks/CU x 256 CU (no tail) ----
#define NETD 16          // e-tiles of 48
#define TND 48           // e-cols per block
#define NCH 24           // chunks per block (all 768 c)
#define M01W 36          // Mt01 row stride in u32 (144 B)
#define NTD 384          // 6 waves = 3 e-subs x 2 s-halves
#define NWGD (BB*NETD)   // 512 blocks

// ---- kZ geometry ----
#define ZT 512
#define NSL 16

typedef __attribute__((ext_vector_type(8))) short short8;   // 8 bf16
typedef __attribute__((ext_vector_type(4))) float f32x4;    // MFMA acc
typedef __attribute__((ext_vector_type(2))) float f32x2;    // packed fp32

__device__ __forceinline__ void gload16(const void* g, void* l) {
    __builtin_amdgcn_global_load_lds(
        (const __attribute__((address_space(1))) unsigned int*)g,
        (__attribute__((address_space(3))) unsigned int*)l, 16, 0, 0);
}

// ---------------------------------------------------------------------------
// kS body: per-b sketch build. u[b,c]=b_sen[c]+sensor·Wsen[c,:];
// CTG[b][c]=(u1, s1, bits(h1c*8), 0)  [h1 pre-scaled to float2-BYTE offset];
// P2G[b][t]=(S2u_b[t], S2s[t]) fp32 pairs.
// ---------------------------------------------------------------------------
__device__ __forceinline__ void kS_body(
    int b, int tid,
    const float* __restrict__ sensor, const float* __restrict__ Wsen,
    const float* __restrict__ bsen,
    const int* __restrict__ h1, const int* __restrict__ h2,
    const int* __restrict__ s1, const int* __restrict__ s2,
    float4* __restrict__ CTG, float2* __restrict__ P2G, float2* P2l,
    float* sens)
{
    if (tid < SN) sens[tid] = sensor[b*SN + tid];
    {
        float4* p4 = (float4*)P2l;
        #pragma unroll
        for (int i = 0; i < 8; ++i) p4[tid + i*512] = make_float4(0.f,0.f,0.f,0.f);
    }
    __syncthreads();

    for (int c = tid; c < CC; c += 512) {
        float u = bsen[c];
        const float4* w = (const float4*)(Wsen + (size_t)c*SN);
        #pragma unroll
        for (int n4 = 0; n4 < 16; ++n4) {
            float4 wv = w[n4];
            u += sens[4*n4+0]*wv.x + sens[4*n4+1]*wv.y
               + sens[4*n4+2]*wv.z + sens[4*n4+3]*wv.w;
        }
        float f1 = (float)s1[c], f2 = (float)s2[c];
        float4 ct;
        ct.x = u * f1; ct.y = f1; ct.z = __int_as_float(h1[c] << 3); ct.w = 0.f;
        CTG[(size_t)b*CC + c] = ct;
        int t = h2[c];
        unsafeAtomicAdd(&P2l[t].x, u * f2);
        unsafeAtomicAdd(&P2l[t].y, f2);
    }
    __syncthreads();

    {
        const float4* p4 = (const float4*)P2l;
        float4* dst = (float4*)(P2G + (size_t)b*DD);
        #pragma unroll
        for (int i = 0; i < 8; ++i) dst[tid + i*512] = p4[tid + i*512];
    }
}

__device__ __forceinline__ void kA_body(
    int bid, int tid,
    const float* __restrict__ E, const float* __restrict__ tok,
    const int* __restrict__ s1, unsigned int* __restrict__ A1u)
{
    if (tid >= 384) return;
    const int b  = bid / 10;
    const int r0 = (bid % 10) * 16;
    const int c  = 2*tid;
    const int ck = tid >> 4;
    const int c2 = tid & 15;
    const float s1a = (float)s1[c], s1b = (float)s1[c+1];
    const float ta = tok[CC + c] * s1a, tb = tok[CC + c + 1] * s1b;
    #pragma unroll
    for (int rr = 0; rr < 16; ++rr) {
        int row = r0 + rr;
        unsigned int word = 0;
        if (row < SS) {
            float2 ev = *(const float2*)&E[((size_t)b*SS + row)*CC + c];
            __hip_bfloat16 x0 = __float2bfloat16(ev.x*s1a + ta);
            __hip_bfloat16 x1 = __float2bfloat16(ev.y*s1b + tb);
            word = (unsigned int)*(unsigned short*)&x0
                 | ((unsigned int)*(unsigned short*)&x1 << 16);
        }
        int gp = (c2 >> 2) ^ (row & 3);
        A1u[((size_t)(b*NCKA + ck)*SROWS + row)*16 + gp*4 + (c2 & 3)] = word;
    }
}

// ---------------------------------------------------------------------------
// kSA (fused path): blocks [0,320) build A1u; [320,352) per-b sketch (kS);
// block 320 also zeroes Q.
// ---------------------------------------------------------------------------
__global__ __launch_bounds__(512) void kSA(
    const float* __restrict__ sensor, const float* __restrict__ Wsen,
    const float* __restrict__ bsen,
    const int* __restrict__ h1, const int* __restrict__ h2,
    const int* __restrict__ s1, const int* __restrict__ s2,
    float4* __restrict__ CTG, float2* __restrict__ P2G,
    const float* __restrict__ E, const float* __restrict__ tok,
    unsigned int* __restrict__ A1u, float* __restrict__ Q)
{
    __shared__ float2 P2l[DD];
    __shared__ float  sens[SN];
    const int bid = blockIdx.x;
    const int tid = threadIdx.x;
    if (bid < 320) {
        kA_body(bid, tid, E, tok, s1, A1u);
    } else {
        if (bid == 320) for (int i = tid; i < BB*SS; i += 512) Q[i] = 0.f;
        kS_body(bid - 320, tid, sensor, Wsen, bsen, h1, h2, s1, s2,
                CTG, P2G, P2l, sens);
    }
}

// kS standalone (fallback path)
__global__ __launch_bounds__(512) void kS(
    const float* __restrict__ sensor, const float* __restrict__ Wsen,
    const float* __restrict__ bsen,
    const int* __restrict__ h1, const int* __restrict__ h2,
    const int* __restrict__ s1, const int* __restrict__ s2,
    float4* __restrict__ CTG, float2* __restrict__ P2G)
{
    __shared__ float2 P2l[DD];
    __shared__ float  sens[SN];
    kS_body(blockIdx.x, threadIdx.x, sensor, Wsen, bsen, h1, h2, s1, s2,
            CTG, P2G, P2l, sens);
}

// ---------------------------------------------------------------------------
// kZ v3 + flag (proven best): 512 thr, 768 iters, unroll 4; byte-offset
// address (sub+and, h1 pre-scaled in kS); packed v_pk_fma_f32 for
// (accU, accC_a); scalar fma for accC_b. Conflict-free b64 gathers.
// Also (bid==0,tid==0) scans bs2 and writes flagP[0] = any(bs2 != 0).
// Writes ZP[b][d]=pack(bf16 Zuu,bf16 Zcr); b==0 also Z11b.
// ---------------------------------------------------------------------------
__global__ __launch_bounds__(ZT) void kZ(
    const float4* __restrict__ CTG, const float2* __restrict__ P2G,
    unsigned int* __restrict__ ZP, unsigned short* __restrict__ Z11b,
    const float* __restrict__ bs2, int* __restrict__ flagP)
{
    __shared__ float2 P2l[DD];        // 64 KB -> 2 blocks/CU

    const int bid = blockIdx.x;
    const int wg  = (bid & 7)*(BB*NSL/8) + (bid >> 3);
    const int b   = wg >> 4;
    const int dsl = wg & (NSL-1);
    const int tid = threadIdx.x;
    const bool doZ11 = (b == 0);

    if (bid == 0 && tid == 0) {
        int f = 0;
        for (int s = 0; s < SS; ++s) f |= (bs2[s] != 0.f) ? 1 : 0;
        *flagP = f;
    }

    {
        const float4* src = (const float4*)(P2G + (size_t)b*DD);
        float4* dst = (float4*)P2l;
        #pragma unroll
        for (int i = 0; i < 8; ++i) dst[tid + i*ZT] = src[tid + i*ZT];
    }
    __syncthreads();

    const int d  = dsl*ZT + tid;
    const int d8 = d << 3;                     // byte offset of own float2
    const float4* ctp = CTG + (size_t)b*CC;
    f32x2 accP = {0.f, 0.f};                   // (accU, accC_a)
    float accC2 = 0.f, acc1 = 0.f;
    #pragma unroll 4
    for (int c = 0; c < CC; ++c) {
        float4 ct = ctp[c];                    // uniform -> s_load path
        int ab = (d8 - __float_as_int(ct.z)) & 65535;   // ((d-h1c)&8191)*8
        f32x2 p = *(const f32x2*)((const char*)P2l + ab);
        f32x2 uu = {ct.x, ct.x};
        accP = __builtin_elementwise_fma(uu, p, accP);  // v_pk_fma_f32
        accC2 = fmaf(ct.y, p.x, accC2);
        if (doZ11) acc1 = fmaf(ct.y, p.y, acc1);
    }
    float accU = accP.x, accC = accP.y + accC2;

    __hip_bfloat16 zu = __float2bfloat16(accU);
    __hip_bfloat16 zc = __float2bfloat16(accC);
    ZP[(size_t)b*DD + d] = (unsigned int)*(unsigned short*)&zu
                         | ((unsigned int)*(unsigned short*)&zc << 16);
    if (doZ11) {
        __hip_bfloat16 z1 = __float2bfloat16(acc1);
        Z11b[d] = *(unsigned short*)&z1;
    }
}

// ---------------------------------------------------------------------------
// kM11: materialize b-independent m=2 matrix (24 blocks). Skipped entirely
// when bs2 == 0 (M11 is then multiplied by bb^2 = 0 and never read).
// ---------------------------------------------------------------------------
__global__ __launch_bounds__(512) void kM11(
    const unsigned short* __restrict__ Z11b,
    const int* __restrict__ h1, const int* __restrict__ h2,
    unsigned int* __restrict__ M11u, const int* __restrict__ flagP)
{
    __shared__ unsigned short Z11l[DD];
    if (*flagP == 0) return;
    const int ck  = blockIdx.x;
    const int tid = threadIdx.x;
    {
        const uint4* src = (const uint4*)Z11b;
        uint4* dst = (uint4*)Z11l;
        #pragma unroll
        for (int i = 0; i < 2; ++i) dst[tid + i*512] = src[tid + i*512];
    }
    __syncthreads();

    #pragma unroll 4
    for (int i = 0; i < 24; ++i) {
        int idx = tid + i*512;
        int ep  = idx >> 4;
        int cpp = idx & 15;
        int ha = h1[ck*32 + 2*cpp];
        int hb = h1[ck*32 + 2*cpp + 1];
        int he = h2[ep];
        unsigned int lo = Z11l[(ha + he) & (DD-1)];
        unsigned int hi = Z11l[(hb + he) & (DD-1)];
        M11u[((size_t)ck*768 + ep)*16 + cpp] = lo | (hi << 16);
    }
}

// kAM (fallback path): kA + kM11 fused; kM11 part honors the flag.
__global__ __launch_bounds__(512) void kAM(
    const float* __restrict__ E, const float* __restrict__ tok,
    const int* __restrict__ s1, unsigned int* __restrict__ A1u,
    const unsigned short* __restrict__ Z11b,
    const int* __restrict__ h1, const int* __restrict__ h2,
    unsigned int* __restrict__ M11u, const int* __restrict__ flagP)
{
    __shared__ unsigned short Z11l[DD];
    const int bid = blockIdx.x;
    const int tid = threadIdx.x;
    if (bid < 320) {
        kA_body(bid, tid, E, tok, s1, A1u);
    } else {
        if (*flagP == 0) return;
        const int ck = bid - 320;
        {
            const uint4* src = (const uint4*)Z11b;
            uint4* dst = (uint4*)Z11l;
            #pragma unroll
            for (int i = 0; i < 2; ++i) dst[tid + i*512] = src[tid + i*512];
        }
        __syncthreads();
        #pragma unroll 4
        for (int i = 0; i < 24; ++i) {
            int idx = tid + i*512;
            int ep  = idx >> 4;
            int cpp = idx & 15;
            int ha = h1[ck*32 + 2*cpp];
            int hb = h1[ck*32 + 2*cpp + 1];
            int he = h2[ep];
            unsigned int lo = Z11l[(ha + he) & (DD-1)];
            unsigned int hi = Z11l[(hb + he) & (DD-1)];
            M11u[((size_t)ck*768 + ep)*16 + cpp] = lo | (hi << 16);
        }
    }
}

// ---------------------------------------------------------------------------
// kD: fused 3-form MFMA; grid 512 no-tail, dbuf Lt/Mt01. When flag==0
// (bs2 all zero), the m=1/m=2 forms are exactly 0: reduced loop with
// 5 MFMA/chunk (b0 only), no M11 loads, vmcnt(0) barriers. Otherwise the
// proven full loop (15 MFMA, counted vmcnt(1)).
// ---------------------------------------------------------------------------
__global__ __launch_bounds__(NTD, 4) void kD(
    const unsigned int* __restrict__ A1u,
    const unsigned short* __restrict__ M11,
    const float* __restrict__ E, const float* __restrict__ tok,
    const int* __restrict__ h1, const int* __restrict__ h2,
    const int* __restrict__ s2,
    const float* __restrict__ Ws2, const float* __restrict__ bs2,
    const unsigned int* __restrict__ ZP, float* __restrict__ Q,
    const int* __restrict__ flagP)
{
    __shared__ __align__(16) unsigned int   ZPl[DD];           // 32768 B
    __shared__ __align__(16) unsigned short Lt[2][SROWS*32];   // 20480 B
    __shared__ __align__(16) unsigned int   Mt01[2][TND*M01W]; // 13824 B
    __shared__ unsigned short h1l[CC];                         //  1536 B

    const int bid = blockIdx.x;
    const int wg  = (bid & 7)*(NWGD/8) + (bid >> 3);
    const int b   = wg / NETD;
    const int et  = wg % NETD;
    const int tid = threadIdx.x;
    const int e0  = et * TND;
    const int fl  = *flagP;

    {
        const uint4* src = (const uint4*)(ZP + (size_t)b*DD);
        uint4* dst = (uint4*)ZPl;
        for (int i = tid; i < DD/4; i += NTD) dst[i] = src[i];
    }
    for (int c = tid; c < CC; c += NTD) h1l[c] = (unsigned short)h1[c];

    const int lane = tid & 63;
    const int wv   = tid >> 6;        // wave 0..5
    const int esub = wv % 3;          // e-sub-tile (16 cols)
    const int shf  = wv / 3;          // s-half
    const int l15  = lane & 15;
    const int l4   = lane >> 4;
    const int eg   = e0 + esub*16 + l15;

    int gh2[4];
    #pragma unroll
    for (int j = 0; j < 4; ++j) gh2[j] = h2[e0 + ((tid + j*NTD) >> 5)];
    __syncthreads();

    const char* Abase = (const char*)A1u + (size_t)b*NCKA*SROWS*64;

#define BARC() do { \
    asm volatile("s_waitcnt vmcnt(1) lgkmcnt(0)" ::: "memory"); \
    __builtin_amdgcn_sched_barrier(0); \
    __builtin_amdgcn_s_barrier(); \
    __builtin_amdgcn_sched_barrier(0); \
} while (0)

#define BARC0() do { \
    asm volatile("s_waitcnt vmcnt(0) lgkmcnt(0)" ::: "memory"); \
    __builtin_amdgcn_sched_barrier(0); \
    __builtin_amdgcn_s_barrier(); \
    __builtin_amdgcn_sched_barrier(0); \
} while (0)

#define STAGE_A(K, BUF) { \
    const char* cbase = Abase + (size_t)(K)*SROWS*64; \
    gload16(cbase + wv*1024 + lane*16, (char*)(BUF) + wv*1024); \
    if (wv < 4) \
        gload16(cbase + 6144 + wv*1024 + lane*16, \
                (char*)(BUF) + 6144 + wv*1024); \
    }

#define GATHER(K, MT) { \
    _Pragma("unroll") \
    for (int j = 0; j < 4; ++j) { \
        int idx = tid + j*NTD; \
        int ge = idx >> 5, gc = idx & 31; \
        int ad = ((int)h1l[(K)*32 + gc] + gh2[j]) & (DD-1); \
        MT[ge*M01W + gc] = ZPl[ad]; \
    } }

#define LOADB2(K) \
    (*(const short8*)&M11[((size_t)(K)*768 + eg)*32 + l4*8])

#define MFMA_STEP(LT, MT, BQ) { \
    const unsigned int* mp = &MT[(esub*16 + l15)*M01W + l4*8]; \
    uint4 p0 = *(const uint4*)mp; \
    uint4 p1 = *(const uint4*)(mp + 4); \
    union { unsigned int u[4]; short8 s; } b0, b1; \
    b0.u[0] = (p0.x & 0xffffu) | (p0.y << 16); \
    b1.u[0] = (p0.x >> 16)     | (p0.y & 0xffff0000u); \
    b0.u[1] = (p0.z & 0xffffu) | (p0.w << 16); \
    b1.u[1] = (p0.z >> 16)     | (p0.w & 0xffff0000u); \
    b0.u[2] = (p1.x & 0xffffu) | (p1.y << 16); \
    b1.u[2] = (p1.x >> 16)     | (p1.y & 0xffff0000u); \
    b0.u[3] = (p1.z & 0xffffu) | (p1.w << 16); \
    b1.u[3] = (p1.z >> 16)     | (p1.w & 0xffff0000u); \
    _Pragma("unroll") \
    for (int t = 0; t < 5; ++t) { \
        int R = shf*80 + t*16 + l15; \
        short8 af = *(const short8*)&LT[R*32 + ((l4 ^ (R & 3))*8)]; \
        acc0[t] = __builtin_amdgcn_mfma_f32_16x16x32_bf16(af, b0.s, acc0[t], 0,0,0); \
        acc1[t] = __builtin_amdgcn_mfma_f32_16x16x32_bf16(af, b1.s, acc1[t], 0,0,0); \
        acc2[t] = __builtin_amdgcn_mfma_f32_16x16x32_bf16(af, BQ,   acc2[t], 0,0,0); \
    } }

#define MFMA_STEP0(LT, MT) { \
    const unsigned int* mp = &MT[(esub*16 + l15)*M01W + l4*8]; \
    uint4 p0 = *(const uint4*)mp; \
    uint4 p1 = *(const uint4*)(mp + 4); \
    union { unsigned int u[4]; short8 s; } b0; \
    b0.u[0] = (p0.x & 0xffffu) | (p0.y << 16); \
    b0.u[1] = (p0.z & 0xffffu) | (p0.w << 16); \
    b0.u[2] = (p1.x & 0xffffu) | (p1.y << 16); \
    b0.u[3] = (p1.z & 0xffffu) | (p1.w << 16); \
    _Pragma("unroll") \
    for (int t = 0; t < 5; ++t) { \
        int R = shf*80 + t*16 + l15; \
        short8 af = *(const short8*)&LT[R*32 + ((l4 ^ (R & 3))*8)]; \
        acc0[t] = __builtin_amdgcn_mfma_f32_16x16x32_bf16(af, b0.s, acc0[t], 0,0,0); \
    } }

    f32x4 acc0[5], acc1[5], acc2[5];
    #pragma unroll
    for (int t = 0; t < 5; ++t) {
        acc0[t] = (f32x4){0.f,0.f,0.f,0.f};
        acc1[t] = (f32x4){0.f,0.f,0.f,0.f};
        acc2[t] = (f32x4){0.f,0.f,0.f,0.f};
    }

    if (fl) {
        short8 bqA, bqB;
        STAGE_A(0, Lt[0])
        GATHER(0, Mt01[0])
        __builtin_amdgcn_sched_barrier(0);
        bqA = LOADB2(0);
        BARC();

        #pragma unroll 1
        for (int k = 0; k < NCH; k += 2) {
            if (k + 1 < NCH) {
                STAGE_A(k + 1, Lt[1])
                GATHER(k + 1, Mt01[1])
                __builtin_amdgcn_sched_barrier(0);
                bqB = LOADB2(k + 1);
            }
            MFMA_STEP(Lt[0], Mt01[0], bqA)
            BARC();

            if (k + 2 < NCH) {
                STAGE_A(k + 2, Lt[0])
                GATHER(k + 2, Mt01[0])
                __builtin_amdgcn_sched_barrier(0);
                bqA = LOADB2(k + 2);
            }
            if (k + 1 < NCH) {
                MFMA_STEP(Lt[1], Mt01[1], bqB)
            }
            BARC();
        }
    } else {
        STAGE_A(0, Lt[0])
        GATHER(0, Mt01[0])
        BARC0();

        #pragma unroll 1
        for (int k = 0; k < NCH; k += 2) {
            if (k + 1 < NCH) {
                STAGE_A(k + 1, Lt[1])
                GATHER(k + 1, Mt01[1])
            }
            MFMA_STEP0(Lt[0], Mt01[0])
            BARC0();

            if (k + 2 < NCH) {
                STAGE_A(k + 2, Lt[0])
                GATHER(k + 2, Mt01[0])
            }
            if (k + 1 < NCH) {
                MFMA_STEP0(Lt[1], Mt01[1])
            }
            BARC0();
        }
    }
#undef BARC
#undef BARC0
#undef STAGE_A
#undef GATHER
#undef LOADB2
#undef MFMA_STEP
#undef MFMA_STEP0

    // --- epilogue: combine 3 forms (acc1/acc2 zero on reduced path),
    //     reduce 16 e-lanes, one atomic ---
    const float s2e = (float)s2[eg];
    const float t2e = tok[CC + eg] * s2e;
    #pragma unroll
    for (int t = 0; t < 5; ++t) {
        #pragma unroll
        for (int rr = 0; rr < 4; ++rr) {
            int s = shf*80 + t*16 + l4*4 + rr;
            float qv = 0.f;
            if (s < SS) {
                float a2v = E[((size_t)b*SS + s)*CC + eg] * s2e + t2e;
                float w2v = Ws2[s], bbv = bs2[s];
                qv = (w2v*w2v*acc0[t][rr] + w2v*bbv*acc1[t][rr]
                      + bbv*bbv*acc2[t][rr]) * a2v;
            }
            qv += __shfl_xor(qv, 1);
            qv += __shfl_xor(qv, 2);
            qv += __shfl_xor(qv, 4);
            qv += __shfl_xor(qv, 8);
            if (l15 == 0 && s < SS)
                unsafeAtomicAdd(&Q[b*SS + s], qv);
        }
    }
}

// ---------------------------------------------------------------------------
// kE: bp = sign(Q)*sqrt(|Q|+1e-5); L2-normalize over s; project W_out.
// ---------------------------------------------------------------------------
__global__ __launch_bounds__(256) void kE(
    const float* __restrict__ Q, const float* __restrict__ Wout,
    const float* __restrict__ bout, float* __restrict__ out)
{
    __shared__ float red[8];
    const int b = blockIdx.x, tid = threadIdx.x;
    float v = 0.f, w = 0.f;
    if (tid < SS) {
        float ip = Q[b*SS + tid];
        float sg = (ip > 0.f) ? 1.f : ((ip < 0.f) ? -1.f : 0.f);
        v = sg * sqrtf(fabsf(ip) + 1e-5f);
        w = v * Wout[tid];
    }
    float sq = v * v;
    #pragma unroll
    for (int off = 32; off > 0; off >>= 1) {
        sq += __shfl_down(sq, off, 64);
        w  += __shfl_down(w,  off, 64);
    }
    if ((tid & 63) == 0) { red[tid >> 6] = sq; red[4 + (tid >> 6)] = w; }
    __syncthreads();
    if (tid == 0) {
        float ssq  = red[0] + red[1] + red[2] + red[3];
        float sw   = red[4] + red[5] + red[6] + red[7];
        float norm = fmaxf(sqrtf(ssq), 1e-12f);
        out[b] = sw / norm + bout[0];
    }
}

// ---------------------------------------------------------------------------
extern "C" void kernel_launch(void* const* d_in, const int* in_sizes, int n_in,
                              void* d_out, int out_size, void* d_ws, size_t ws_size,
                              hipStream_t stream) {
    const float* sensor = (const float*)d_in[0];
    const float* E      = (const float*)d_in[1];
    const int*   h1     = (const int*)d_in[3];
    const int*   h2     = (const int*)d_in[4];
    const int*   s1     = (const int*)d_in[5];
    const int*   s2     = (const int*)d_in[6];
    const float* Wsen   = (const float*)d_in[8];
    const float* bsen   = (const float*)d_in[9];
    const float* Ws2    = (const float*)d_in[10];
    const float* bs2    = (const float*)d_in[11];
    const float* Wout   = (const float*)d_in[12];
    const float* bout   = (const float*)d_in[13];
    const float* tok    = (const float*)d_in[14];
    float* out = (float*)d_out;

    char* ws = (char*)d_ws;
    const size_t SZ_CTG  = (size_t)BB*CC*16;        //   393,216
    const size_t SZ_P2G  = (size_t)BB*DD*8;         // 2,097,152
    const size_t SZ_ZP   = (size_t)BB*DD*4;         // 1,048,576
    const size_t SZ_Z11  = (size_t)DD*2;            //    16,384
    const size_t SZ_M11  = (size_t)NCKA*768*64;     // 1,179,648
    const size_t SZ_Q    = (size_t)BB*SS*4;         //    18,560
    const size_t SZ_FLAG = 64;
    const size_t SZ_A1   = (size_t)BB*NCKA*SROWS*64;// 7,864,320
    const size_t needFused =
        SZ_CTG+SZ_P2G+SZ_ZP+SZ_Z11+SZ_M11+SZ_Q+SZ_FLAG+SZ_A1;

    if (ws_size >= needFused) {
        // ---- fused path: A1u non-aliased, kA runs concurrently with kS ----
        float4* CTG = (float4*)ws;
        float2* P2G = (float2*)(ws + SZ_CTG);
        unsigned int*   ZP   = (unsigned int*)(ws + SZ_CTG + SZ_P2G);
        unsigned short* Z11b = (unsigned short*)((char*)ZP + SZ_ZP);
        unsigned int*   M11u = (unsigned int*)((char*)Z11b + SZ_Z11);
        float*          Q    = (float*)((char*)M11u + SZ_M11);
        int*            flagP= (int*)((char*)Q + SZ_Q);
        unsigned int*   A1u  = (unsigned int*)((char*)flagP + SZ_FLAG);

        kSA<<<dim3(352), dim3(512), 0, stream>>>(
            sensor, Wsen, bsen, h1, h2, s1, s2, CTG, P2G, E, tok, A1u, Q);
        kZ<<<dim3(BB*NSL), dim3(ZT), 0, stream>>>(
            CTG, P2G, ZP, Z11b, bs2, flagP);
        kM11<<<dim3(NCKA), dim3(512), 0, stream>>>(Z11b, h1, h2, M11u, flagP);
        kD<<<dim3(NWGD), dim3(NTD), 0, stream>>>(
            A1u, (const unsigned short*)M11u, E, tok, h1, h2, s2,
            Ws2, bs2, ZP, Q, flagP);
        kE<<<dim3(BB), dim3(256), 0, stream>>>(Q, Wout, bout, out);
    } else {
        // ---- fallback: A1u aliases CTG/P2G after kZ ----
        float4* CTG = (float4*)ws;
        float2* P2G = (float2*)(ws + SZ_CTG);
        unsigned int* A1u = (unsigned int*)ws;
        unsigned int*   ZP   = (unsigned int*)(ws + SZ_A1);
        unsigned short* Z11b = (unsigned short*)(ws + SZ_A1 + SZ_ZP);
        unsigned int*   M11u = (unsigned int*)((char*)Z11b + SZ_Z11);
        float* Q = (float*)((char*)M11u + SZ_M11);
        int*   flagP = (int*)((char*)Q + SZ_Q);

        hipMemsetAsync(Q, 0, SZ_Q, stream);
        kS<<<dim3(BB), dim3(512), 0, stream>>>(
            sensor, Wsen, bsen, h1, h2, s1, s2, CTG, P2G);
        kZ<<<dim3(BB*NSL), dim3(ZT), 0, stream>>>(
            CTG, P2G, ZP, Z11b, bs2, flagP);
        kAM<<<dim3(344), dim3(512), 0, stream>>>(
            E, tok, s1, A1u, Z11b, h1, h2, M11u, flagP);
        kD<<<dim3(NWGD), dim3(NTD), 0, stream>>>(
            A1u, (const unsigned short*)M11u, E, tok, h1, h2, s2,
            Ws2, bs2, ZP, Q, flagP);
        kE<<<dim3(BB), dim3(256), 0, stream>>>(Q, Wout, bout, out);
    }
}